// Round 8
// baseline (336.468 us; speedup 1.0000x reference)
//
#include <hip/hip_runtime.h>
#include <math.h>

#define N_NODES 100000
#define C 64
#define EPS 1e-9f
#define SCAN_BLK 1024
#define NXCD 8
#define NG 4
#define RNG (N_NODES / NG)            // 25000 src rows per g-bucket
#define SLICE_N (N_NODES / NXCD)      // 12500 dst rows per slice
#define KEYS (N_NODES * NG)           // 400000 (dst,g) keys == position count
#define NBLKK ((KEYS + SCAN_BLK - 1) / SCAN_BLK)   // 391
#define GCH 500
#define NPC (N_NODES / GCH)           // 200 positions/chunk
#define NDH ((N_NODES + 255) / 256)   // 391 blocks for per-node kernels

typedef __attribute__((ext_vector_type(8))) short bf16x8;
typedef __attribute__((ext_vector_type(4))) float f32x4;
typedef unsigned short u16;

__device__ __forceinline__ unsigned short f2bf(float f) {
    union { float f; unsigned int u; } v; v.f = f;
    unsigned int u = v.u;
    return (unsigned short)((u + 0x7FFFu + ((u >> 16) & 1u)) >> 16);
}

// ===========================================================================
// Generic scan kernels
// ===========================================================================
__global__ void scan_block_kernel(const int* __restrict__ cnt, int* __restrict__ off,
                                  int* __restrict__ bsum, int n) {
    __shared__ int tmp[SCAN_BLK];
    int tid = threadIdx.x;
    int gid = blockIdx.x * SCAN_BLK + tid;
    int v = (gid < n) ? cnt[gid] : 0;
    tmp[tid] = v;
    __syncthreads();
    for (int d = 1; d < SCAN_BLK; d <<= 1) {
        int t = (tid >= d) ? tmp[tid - d] : 0;
        __syncthreads();
        tmp[tid] += t;
        __syncthreads();
    }
    if (gid < n) off[gid] = tmp[tid] - v;
    if (tid == SCAN_BLK - 1) bsum[blockIdx.x] = tmp[tid];
}

__global__ void scan_bsum_kernel(int* __restrict__ bsum, int nb) {
    __shared__ int tmp[512];
    int tid = threadIdx.x;
    int v = (tid < nb) ? bsum[tid] : 0;
    tmp[tid] = v;
    __syncthreads();
    for (int d = 1; d < 512; d <<= 1) {
        int t = (tid >= d) ? tmp[tid - d] : 0;
        __syncthreads();
        tmp[tid] += t;
        __syncthreads();
    }
    if (tid < nb) bsum[tid] = tmp[tid] - v;
}

__global__ void scan_add_kernel(int* __restrict__ off, const int* __restrict__ bsum,
                                int* __restrict__ dummy, int n, int E) {
    int gid = blockIdx.x * SCAN_BLK + threadIdx.x;
    if (gid < n) {
        int v = off[gid] + bsum[blockIdx.x];
        off[gid] = v;
        dummy[gid] = v;
    }
    if (gid == 0) off[n] = E;
}

// ===========================================================================
// K0: partition edges into 8 dst-range buckets (per-slice (key16,src) arrays)
// ===========================================================================
__global__ void __launch_bounds__(256)
partition_kernel(const int* __restrict__ src, const int* __restrict__ dst,
                 int* __restrict__ bcur, u16* __restrict__ bkey16,
                 int* __restrict__ bsrc, int E, int bcap) {
    __shared__ int lcnt[NXCD];
    __shared__ int lbase[NXCD];
    const int tid = threadIdx.x;
    const int per = (E + gridDim.x - 1) / gridDim.x;
    const int i0 = blockIdx.x * per;
    const int i1 = min(i0 + per, E);

    if (tid < NXCD) lcnt[tid] = 0;
    __syncthreads();
    for (int i = i0 + tid; i < i1; i += 256)
        atomicAdd(&lcnt[dst[i] / SLICE_N], 1);
    __syncthreads();
    if (tid < NXCD) {
        lbase[tid] = atomicAdd(&bcur[tid], lcnt[tid]);
        lcnt[tid] = 0;
    }
    __syncthreads();
    for (int i = i0 + tid; i < i1; i += 256) {
        int d  = dst[i];
        int sv = src[i];
        int s  = d / SLICE_N;
        int p  = lbase[s] + atomicAdd(&lcnt[s], 1);
        size_t pos = (size_t)s * bcap + p;
        bkey16[pos] = (u16)((d - s * SLICE_N) * NG + sv / RNG);
        bsrc[pos] = sv;
    }
}

// hist over bucketed keys; slice-s atomics stay in a 200KB XCD-local region.
__global__ void hist2p_kernel(const int* __restrict__ bcur,
                              const u16* __restrict__ bkey16,
                              int* __restrict__ cnt2, int bcap) {
    const int s = blockIdx.x & (NXCD - 1);
    const int bn = bcur[s];
    const u16* __restrict__ k = bkey16 + (size_t)s * bcap;
    int* __restrict__ c2 = cnt2 + s * (SLICE_N * NG);
    const int stride = (gridDim.x >> 3) * blockDim.x;
    for (int i = (blockIdx.x >> 3) * blockDim.x + threadIdx.x; i < bn; i += stride)
        atomicAdd(&c2[k[i]], 1);
}

__global__ void build2p_kernel(const int* __restrict__ bcur,
                               const u16* __restrict__ bkey16,
                               const int* __restrict__ bsrc,
                               int* __restrict__ cursor2, int* __restrict__ csr,
                               int bcap) {
    const int s = blockIdx.x & (NXCD - 1);
    const int bn = bcur[s];
    const u16* __restrict__ k  = bkey16 + (size_t)s * bcap;
    const int* __restrict__ sv = bsrc + (size_t)s * bcap;
    int* __restrict__ cur = cursor2 + s * (SLICE_N * NG);
    const int stride = (gridDim.x >> 3) * blockDim.x;
    for (int i = (blockIdx.x >> 3) * blockDim.x + threadIdx.x; i < bn; i += stride) {
        int p = atomicAdd(&cur[k[i]], 1);
        csr[p] = sv[i];
    }
}

// Tier-B hist/build (no bucket arrays): direct 8x edge-list streaming
__global__ void hist2_kernel(const int* __restrict__ src, const int* __restrict__ dst,
                             int* __restrict__ cnt2, int E) {
    const int s  = blockIdx.x & (NXCD - 1);
    const int lo = s * SLICE_N;
    const int hi = lo + SLICE_N;
    const int stride = (gridDim.x >> 3) * blockDim.x;
    for (int i = (blockIdx.x >> 3) * blockDim.x + threadIdx.x; i < E; i += stride) {
        int d = dst[i];
        if (d >= lo && d < hi) {
            int g = src[i] / RNG;
            atomicAdd(&cnt2[d * NG + g], 1);
        }
    }
}

__global__ void build2_kernel(const int* __restrict__ src, const int* __restrict__ dst,
                              int* __restrict__ cursor2, int* __restrict__ csr, int E) {
    const int s  = blockIdx.x & (NXCD - 1);
    const int lo = s * SLICE_N;
    const int hi = lo + SLICE_N;
    const int stride = (gridDim.x >> 3) * blockDim.x;
    for (int i = (blockIdx.x >> 3) * blockDim.x + threadIdx.x; i < E; i += stride) {
        int d = dst[i];
        if (d >= lo && d < hi) {
            int sv = src[i];
            int g = sv / RNG;
            int p = atomicAdd(&cursor2[d * NG + g], 1);
            csr[p] = sv;
        }
    }
}

// ===========================================================================
// Degree-class ordering over (n,g) counts. Global exclusive scan over the
// 128 [g][class] bins yields g-major position space [g*N, (g+1)*N).
// ===========================================================================
__global__ void __launch_bounds__(256)
deg_class_kernel(const int* __restrict__ cnt2, int* __restrict__ dh,
                 int* __restrict__ degT) {
    __shared__ int lh[128];
    const int tid = threadIdx.x;
    if (tid < 128) lh[tid] = 0;
    __syncthreads();
    const int n = blockIdx.x * 256 + tid;
    if (n < N_NODES) {
        int4 c4 = *(const int4*)(cnt2 + 4 * n);
        degT[n] = c4.x + c4.y + c4.z + c4.w;
        atomicAdd(&lh[ 0 + min(c4.x, 31)], 1);
        atomicAdd(&lh[32 + min(c4.y, 31)], 1);
        atomicAdd(&lh[64 + min(c4.z, 31)], 1);
        atomicAdd(&lh[96 + min(c4.w, 31)], 1);
    }
    __syncthreads();
    if (tid < 128 && lh[tid]) atomicAdd(&dh[tid], lh[tid]);
}

__global__ void __launch_bounds__(128)
scan_deg_kernel(int* __restrict__ dh, int* __restrict__ dcur) {
    __shared__ int tmp[128];
    const int tid = threadIdx.x;
    int v = dh[tid];
    tmp[tid] = v;
    __syncthreads();
    for (int d = 1; d < 128; d <<= 1) {
        int t = (tid >= d) ? tmp[tid - d] : 0;
        __syncthreads();
        tmp[tid] += t;
        __syncthreads();
    }
    int excl = tmp[tid] - v;
    dh[tid] = excl;
    dcur[tid] = excl;
}

// ord[p] = node at global position p; posOf[4n+g] = p (inverse permutation)
__global__ void __launch_bounds__(256)
deg_scatter_kernel(const int* __restrict__ cnt2, int* __restrict__ dcur,
                   int* __restrict__ ord, int* __restrict__ posOf) {
    __shared__ int lcnt[128];
    __shared__ int lbase[128];
    __shared__ u16 lrank[1024];
    __shared__ unsigned char lcls[1024];
    const int tid = threadIdx.x;
    if (tid < 128) lcnt[tid] = 0;
    __syncthreads();
    const int n = blockIdx.x * 256 + tid;
    if (n < N_NODES) {
        int4 c4 = *(const int4*)(cnt2 + 4 * n);
        int dg[4] = { c4.x, c4.y, c4.z, c4.w };
#pragma unroll
        for (int g = 0; g < 4; ++g) {
            int c = g * 32 + min(dg[g], 31);
            lcls[tid * 4 + g]  = (unsigned char)c;
            lrank[tid * 4 + g] = (u16)atomicAdd(&lcnt[c], 1);
        }
    }
    __syncthreads();
    if (tid < 128) lbase[tid] = lcnt[tid] ? atomicAdd(&dcur[tid], lcnt[tid]) : 0;
    __syncthreads();
    if (n < N_NODES) {
#pragma unroll
        for (int g = 0; g < 4; ++g) {
            int c = lcls[tid * 4 + g];
            int p = lbase[c] + lrank[tid * 4 + g];
            ord[p] = n;
            posOf[4 * n + g] = p;
        }
    }
}

// cperm[p] = count of the (n,g) pair living at position p
__global__ void __launch_bounds__(256)
cperm_fill_kernel(const int* __restrict__ ord, const int* __restrict__ cnt2,
                  int* __restrict__ cperm) {
    int p = blockIdx.x * 256 + threadIdx.x;
    if (p < KEYS) {
        int g = p / N_NODES;
        int n = ord[p];
        cperm[p] = cnt2[4 * n + g];
    }
}

// cursor2[key] = offp[posOf[key]]  (CSR is built directly in permuted layout)
__global__ void __launch_bounds__(256)
cursor_init_kernel(const int* __restrict__ offp, const int* __restrict__ posOf,
                   int* __restrict__ cursor2) {
    int k = blockIdx.x * 256 + threadIdx.x;
    if (k < KEYS) cursor2[k] = offp[posOf[k]];
}

// ===========================================================================
// K4: XCD-sliced gather over permuted positions. All of offp/csr accesses are
// CONTIGUOUS in position space; 8 chains per wave have equal trip counts
// (same degree class). Slice (g,h) x-footprint = 25000x128B = 3.2MB (L2).
// Only the P-row store is scattered (full 128B nontemporal line).
// ===========================================================================
__global__ void __launch_bounds__(256)
gatherP_kernel(const float* __restrict__ x, const int* __restrict__ offp,
               const int* __restrict__ csr, const int* __restrict__ ord,
               float* __restrict__ P0, float* __restrict__ P1,
               float* __restrict__ P2, float* __restrict__ P3) {
    const int sid = blockIdx.x & (NXCD - 1);
    const int g = sid >> 1;
    const int h = sid & 1;
    float* __restrict__ P = (g == 0) ? P0 : (g == 1) ? P1 : (g == 2) ? P2 : P3;
    const int chunk = blockIdx.x >> 3;          // < GCH
    const int pos0 = chunk * NPC;
    const int wid  = threadIdx.x >> 6;
    const int lane = threadIdx.x & 63;
    const int r  = lane >> 5;                   // edge parity
    const int cc = lane & 31;                   // channel within half
    const float* __restrict__ xs = x + h * 32 + cc;
    const int* __restrict__ ordg = ord + g * N_NODES;
    const int* __restrict__ offg = offp + g * N_NODES;

    for (int p0 = pos0 + 8 * wid; p0 < pos0 + NPC; p0 += 32) {
        int ni[8], j[8], e[8];
        float s[8];
#pragma unroll
        for (int i = 0; i < 8; ++i) {
            ni[i] = ordg[p0 + i];
            j[i] = offg[p0 + i] + r;
            e[i] = offg[p0 + i + 1];
            s[i] = 0.0f;
        }

        while (true) {
            bool p[8];
            bool any = false;
#pragma unroll
            for (int i = 0; i < 8; ++i) { p[i] = j[i] < e[i]; any = any || p[i]; }
            if (!any) break;

            float t[8];
#pragma unroll
            for (int i = 0; i < 8; ++i) {
                int q = csr[p[i] ? j[i] : 0];
                t[i] = xs[(size_t)q * C];
            }
#pragma unroll
            for (int i = 0; i < 8; ++i) {
                s[i] += p[i] ? t[i] : 0.0f;
                j[i] += 2;
            }
        }

#pragma unroll
        for (int i = 0; i < 8; ++i)
            s[i] += __shfl_xor(s[i], 32);
        if (r == 0) {
#pragma unroll
            for (int i = 0; i < 8; ++i)
                __builtin_nontemporal_store(s[i], &P[(size_t)ni[i] * C + h * 32 + cc]);
        }
    }
}

// ===========================================================================
// K5: GEMM [mean|x](100K x 128) @ [Wl;Wr]^T via mfma_f32_16x16x32_bf16.
// Fused bias+relu+L2norm epilogue. P3 = d_out read-before-write (tile-local).
// ===========================================================================
__global__ void __launch_bounds__(256)
transform_mfma_kernel(const float* __restrict__ x, const int* __restrict__ degT,
                      const float* __restrict__ P0, const float* __restrict__ P1,
                      const float* __restrict__ P2, const float* __restrict__ P3,
                      const float* __restrict__ Wl, const float* __restrict__ bl,
                      const float* __restrict__ Wr, float* __restrict__ out) {
    const int lane = threadIdx.x & 63;
    const int wid  = threadIdx.x >> 6;
    const int col  = lane & 15;
    const int lg   = lane >> 4;

    bf16x8 Bf[4][4];
    float bias[4];
#pragma unroll
    for (int cb = 0; cb < 4; ++cb) {
        const int cc = cb * 16 + col;
        bias[cb] = bl[cc];
#pragma unroll
        for (int ks = 0; ks < 4; ++ks) {
            const int kk0 = ks * 32 + lg * 8;
            const float* W = (kk0 < 64) ? (Wl + (size_t)cc * 64 + kk0)
                                        : (Wr + (size_t)cc * 64 + (kk0 - 64));
            float4 w0 = *(const float4*)W;
            float4 w1 = *(const float4*)(W + 4);
            bf16x8 b;
            b[0]=(short)f2bf(w0.x); b[1]=(short)f2bf(w0.y);
            b[2]=(short)f2bf(w0.z); b[3]=(short)f2bf(w0.w);
            b[4]=(short)f2bf(w1.x); b[5]=(short)f2bf(w1.y);
            b[6]=(short)f2bf(w1.z); b[7]=(short)f2bf(w1.w);
            Bf[cb][ks] = b;
        }
    }

    const int ntiles = N_NODES / 16;
    for (int t = blockIdx.x * 4 + wid; t < ntiles; t += gridDim.x * 4) {
        const int n0 = t * 16;
        const int arow = n0 + col;
        const int deg = degT[arow];
        const float inv = 1.0f / (float)(deg > 1 ? deg : 1);

        f32x4 acc[4];
#pragma unroll
        for (int cb = 0; cb < 4; ++cb) acc[cb] = f32x4{0.f, 0.f, 0.f, 0.f};

#pragma unroll
        for (int ks = 0; ks < 4; ++ks) {
            const int kk0 = ks * 32 + lg * 8;
            bf16x8 a;
            if (kk0 < 64) {
                const float4* p0 = (const float4*)(P0 + (size_t)arow * C + kk0);
                const float4* p1 = (const float4*)(P1 + (size_t)arow * C + kk0);
                const float4* p2 = (const float4*)(P2 + (size_t)arow * C + kk0);
                const float4* p3 = (const float4*)(P3 + (size_t)arow * C + kk0);
                float4 a0 = p0[0], b0 = p1[0], c0 = p2[0], e0 = p3[0];
                float4 a1 = p0[1], b1 = p1[1], c1 = p2[1], e1 = p3[1];
                float s0x = ((a0.x + b0.x) + (c0.x + e0.x)) * inv;
                float s0y = ((a0.y + b0.y) + (c0.y + e0.y)) * inv;
                float s0z = ((a0.z + b0.z) + (c0.z + e0.z)) * inv;
                float s0w = ((a0.w + b0.w) + (c0.w + e0.w)) * inv;
                float s1x = ((a1.x + b1.x) + (c1.x + e1.x)) * inv;
                float s1y = ((a1.y + b1.y) + (c1.y + e1.y)) * inv;
                float s1z = ((a1.z + b1.z) + (c1.z + e1.z)) * inv;
                float s1w = ((a1.w + b1.w) + (c1.w + e1.w)) * inv;
                a[0]=(short)f2bf(s0x); a[1]=(short)f2bf(s0y);
                a[2]=(short)f2bf(s0z); a[3]=(short)f2bf(s0w);
                a[4]=(short)f2bf(s1x); a[5]=(short)f2bf(s1y);
                a[6]=(short)f2bf(s1z); a[7]=(short)f2bf(s1w);
            } else {
                const float4* xp = (const float4*)(x + (size_t)arow * C + (kk0 - 64));
                float4 v0 = xp[0], v1 = xp[1];
                a[0]=(short)f2bf(v0.x); a[1]=(short)f2bf(v0.y);
                a[2]=(short)f2bf(v0.z); a[3]=(short)f2bf(v0.w);
                a[4]=(short)f2bf(v1.x); a[5]=(short)f2bf(v1.y);
                a[6]=(short)f2bf(v1.z); a[7]=(short)f2bf(v1.w);
            }
#pragma unroll
            for (int cb = 0; cb < 4; ++cb)
                acc[cb] = __builtin_amdgcn_mfma_f32_16x16x32_bf16(a, Bf[cb][ks], acc[cb], 0, 0, 0);
        }

#pragma unroll
        for (int jj = 0; jj < 4; ++jj) {
            float v0 = fmaxf(acc[0][jj] + bias[0], 0.0f);
            float v1 = fmaxf(acc[1][jj] + bias[1], 0.0f);
            float v2 = fmaxf(acc[2][jj] + bias[2], 0.0f);
            float v3 = fmaxf(acc[3][jj] + bias[3], 0.0f);
            float sS = (v0 * v0 + v1 * v1) + (v2 * v2 + v3 * v3);
            sS += __shfl_xor(sS, 1);
            sS += __shfl_xor(sS, 2);
            sS += __shfl_xor(sS, 4);
            sS += __shfl_xor(sS, 8);
            float rr = 1.0f / (sqrtf(sS) + EPS);
            const int n = n0 + lg * 4 + jj;
            float* o = out + (size_t)n * C + col;
            o[0]  = v0 * rr;
            o[16] = v1 * rr;
            o[32] = v2 * rr;
            o[48] = v3 * rr;
        }
    }
}

// ===========================================================================
extern "C" void kernel_launch(void* const* d_in, const int* in_sizes, int n_in,
                              void* d_out, int out_size, void* d_ws, size_t ws_size,
                              hipStream_t stream) {
    const float* x    = (const float*)d_in[0];
    const int*   edge = (const int*)d_in[1];
    const float* Wl   = (const float*)d_in[2];
    const float* bl   = (const float*)d_in[3];
    const float* Wr   = (const float*)d_in[4];

    const int E = in_sizes[1] / 2;
    const int* src = edge;
    const int* dst = edge + E;
    const int Epad = (E + 3) & ~3;
    const int bcap = E / NXCD + 32768;

    const size_t nc = (size_t)N_NODES * C;

    // layout: P0 P1 P2 | cnt2 bcur dh dcur degT posOf cursor2 offp bsum
    //         cperm csr ord | bsrc bkey16
    float* P0    = (float*)d_ws;
    float* P1    = P0 + nc;
    float* P2    = P1 + nc;
    int* cnt2    = (int*)(P2 + nc);        // KEYS
    int* bcur    = cnt2 + KEYS;            // 8
    int* dh      = bcur + 8;               // 128
    int* dcur    = dh + 128;               // 128
    int* degT    = dcur + 128;             // N
    int* posOf   = degT + N_NODES;         // KEYS
    int* cursor2 = posOf + KEYS;           // KEYS
    int* offp    = cursor2 + KEYS;         // KEYS+4 reserved
    int* bsum    = offp + KEYS + 4;        // 512
    int* cperm   = bsum + 512;             // KEYS
    int* csr     = cperm + KEYS;           // Epad
    int* ord     = csr + Epad;             // KEYS
    int* bsrc    = ord + KEYS;             // 8*bcap
    u16* bkey16  = (u16*)(bsrc + (size_t)8 * bcap);
    float* P3    = (float*)d_out;

    const size_t baseInts = (size_t)KEYS * 6 + 8 + 256 + N_NODES + 4 + 512 + Epad;
    const size_t needB = 3ull * nc * 4 + baseInts * 4;
    const size_t needA = needB + (size_t)8 * bcap * 6;

    // zero cnt2 + bcur + dh (adjacent); dcur seeded by scan_deg
    hipMemsetAsync(cnt2, 0, (size_t)(KEYS + 8 + 128) * sizeof(int), stream);

    bool tierA = (ws_size >= needA);
    if (tierA) {
        partition_kernel<<<1024, 256, 0, stream>>>(src, dst, bcur, bkey16, bsrc, E, bcap);
        hist2p_kernel<<<NXCD * 96, 256, 0, stream>>>(bcur, bkey16, cnt2, bcap);
    } else {
        hist2_kernel<<<NXCD * 256, 256, 0, stream>>>(src, dst, cnt2, E);
    }

    // degree-class ordering + permuted scan
    deg_class_kernel<<<NDH, 256, 0, stream>>>(cnt2, dh, degT);
    scan_deg_kernel<<<1, 128, 0, stream>>>(dh, dcur);
    deg_scatter_kernel<<<NDH, 256, 0, stream>>>(cnt2, dcur, ord, posOf);
    cperm_fill_kernel<<<(KEYS + 255) / 256, 256, 0, stream>>>(ord, cnt2, cperm);
    scan_block_kernel<<<NBLKK, SCAN_BLK, 0, stream>>>(cperm, offp, bsum, KEYS);
    scan_bsum_kernel<<<1, 512, 0, stream>>>(bsum, NBLKK);
    scan_add_kernel<<<NBLKK, SCAN_BLK, 0, stream>>>(offp, bsum, cperm, KEYS, E);
    cursor_init_kernel<<<(KEYS + 255) / 256, 256, 0, stream>>>(offp, posOf, cursor2);

    if (tierA) {
        build2p_kernel<<<NXCD * 96, 256, 0, stream>>>(bcur, bkey16, bsrc, cursor2, csr, bcap);
    } else {
        build2_kernel<<<NXCD * 256, 256, 0, stream>>>(src, dst, cursor2, csr, E);
    }

    gatherP_kernel<<<NXCD * GCH, 256, 0, stream>>>(x, offp, csr, ord, P0, P1, P2, P3);
    transform_mfma_kernel<<<1024, 256, 0, stream>>>(x, degT, P0, P1, P2, P3,
                                                    Wl, bl, Wr, (float*)d_out);
}

// Round 9
// 330.454 us; speedup vs baseline: 1.0182x; 1.0182x over previous
//
#include <hip/hip_runtime.h>
#include <math.h>

#define N_NODES 100000
#define C 64
#define EPS 1e-9f
#define SCAN_BLK 1024
#define NXCD 8
#define NG 4
#define RNG (N_NODES / NG)            // 25000 src rows per g-bucket
#define SLICE_N (N_NODES / NXCD)      // 12500 dst rows per slice
#define KEYS (N_NODES * NG)           // 400000 (dst,g) keys == position count
#define NBLKK ((KEYS + SCAN_BLK - 1) / SCAN_BLK)   // 391
#define GCH 500
#define NPC (N_NODES / GCH)           // 200 positions/chunk
#define NDH ((N_NODES + 255) / 256)   // 391 blocks for per-node kernels
#define NBINS 1024                    // [g][dst-slice][class] = 4*8*32

typedef __attribute__((ext_vector_type(8))) short bf16x8;
typedef __attribute__((ext_vector_type(4))) float f32x4;
typedef unsigned short u16;

__device__ __forceinline__ unsigned short f2bf(float f) {
    union { float f; unsigned int u; } v; v.f = f;
    unsigned int u = v.u;
    return (unsigned short)((u + 0x7FFFu + ((u >> 16) & 1u)) >> 16);
}

// ===========================================================================
// Generic scan kernels
// ===========================================================================
__global__ void scan_block_kernel(const int* __restrict__ cnt, int* __restrict__ off,
                                  int* __restrict__ bsum, int n) {
    __shared__ int tmp[SCAN_BLK];
    int tid = threadIdx.x;
    int gid = blockIdx.x * SCAN_BLK + tid;
    int v = (gid < n) ? cnt[gid] : 0;
    tmp[tid] = v;
    __syncthreads();
    for (int d = 1; d < SCAN_BLK; d <<= 1) {
        int t = (tid >= d) ? tmp[tid - d] : 0;
        __syncthreads();
        tmp[tid] += t;
        __syncthreads();
    }
    if (gid < n) off[gid] = tmp[tid] - v;
    if (tid == SCAN_BLK - 1) bsum[blockIdx.x] = tmp[tid];
}

__global__ void scan_bsum_kernel(int* __restrict__ bsum, int nb) {
    __shared__ int tmp[512];
    int tid = threadIdx.x;
    int v = (tid < nb) ? bsum[tid] : 0;
    tmp[tid] = v;
    __syncthreads();
    for (int d = 1; d < 512; d <<= 1) {
        int t = (tid >= d) ? tmp[tid - d] : 0;
        __syncthreads();
        tmp[tid] += t;
        __syncthreads();
    }
    if (tid < nb) bsum[tid] = tmp[tid] - v;
}

__global__ void scan_add_kernel(int* __restrict__ off, const int* __restrict__ bsum,
                                int n, int E) {
    int gid = blockIdx.x * SCAN_BLK + threadIdx.x;
    if (gid < n) off[gid] += bsum[blockIdx.x];
    if (gid == 0) off[n] = E;
}

// ===========================================================================
// K0: partition edges into 8 dst-range buckets (per-slice (key16,src) arrays)
// ===========================================================================
__global__ void __launch_bounds__(256)
partition_kernel(const int* __restrict__ src, const int* __restrict__ dst,
                 int* __restrict__ bcur, u16* __restrict__ bkey16,
                 int* __restrict__ bsrc, int E, int bcap) {
    __shared__ int lcnt[NXCD];
    __shared__ int lbase[NXCD];
    const int tid = threadIdx.x;
    const int per = (E + gridDim.x - 1) / gridDim.x;
    const int i0 = blockIdx.x * per;
    const int i1 = min(i0 + per, E);

    if (tid < NXCD) lcnt[tid] = 0;
    __syncthreads();
    for (int i = i0 + tid; i < i1; i += 256)
        atomicAdd(&lcnt[dst[i] / SLICE_N], 1);
    __syncthreads();
    if (tid < NXCD) {
        lbase[tid] = atomicAdd(&bcur[tid], lcnt[tid]);
        lcnt[tid] = 0;
    }
    __syncthreads();
    for (int i = i0 + tid; i < i1; i += 256) {
        int d  = dst[i];
        int sv = src[i];
        int s  = d / SLICE_N;
        int p  = lbase[s] + atomicAdd(&lcnt[s], 1);
        size_t pos = (size_t)s * bcap + p;
        bkey16[pos] = (u16)((d - s * SLICE_N) * NG + sv / RNG);
        bsrc[pos] = sv;
    }
}

// hist over bucketed keys; slice-s atomics stay in a 200KB XCD-local region.
__global__ void hist2p_kernel(const int* __restrict__ bcur,
                              const u16* __restrict__ bkey16,
                              int* __restrict__ cnt2, int bcap) {
    const int s = blockIdx.x & (NXCD - 1);
    const int bn = bcur[s];
    const u16* __restrict__ k = bkey16 + (size_t)s * bcap;
    int* __restrict__ c2 = cnt2 + s * (SLICE_N * NG);
    const int stride = (gridDim.x >> 3) * blockDim.x;
    for (int i = (blockIdx.x >> 3) * blockDim.x + threadIdx.x; i < bn; i += stride)
        atomicAdd(&c2[k[i]], 1);
}

__global__ void build2p_kernel(const int* __restrict__ bcur,
                               const u16* __restrict__ bkey16,
                               const int* __restrict__ bsrc,
                               int* __restrict__ cursor2, int* __restrict__ csr,
                               int bcap) {
    const int s = blockIdx.x & (NXCD - 1);
    const int bn = bcur[s];
    const u16* __restrict__ k  = bkey16 + (size_t)s * bcap;
    const int* __restrict__ sv = bsrc + (size_t)s * bcap;
    int* __restrict__ cur = cursor2 + s * (SLICE_N * NG);
    const int stride = (gridDim.x >> 3) * blockDim.x;
    for (int i = (blockIdx.x >> 3) * blockDim.x + threadIdx.x; i < bn; i += stride) {
        int p = atomicAdd(&cur[k[i]], 1);
        csr[p] = sv[i];
    }
}

// Tier-B hist/build (no bucket arrays): direct 8x edge-list streaming
__global__ void hist2_kernel(const int* __restrict__ src, const int* __restrict__ dst,
                             int* __restrict__ cnt2, int E) {
    const int s  = blockIdx.x & (NXCD - 1);
    const int lo = s * SLICE_N;
    const int hi = lo + SLICE_N;
    const int stride = (gridDim.x >> 3) * blockDim.x;
    for (int i = (blockIdx.x >> 3) * blockDim.x + threadIdx.x; i < E; i += stride) {
        int d = dst[i];
        if (d >= lo && d < hi) {
            int g = src[i] / RNG;
            atomicAdd(&cnt2[d * NG + g], 1);
        }
    }
}

__global__ void build2_kernel(const int* __restrict__ src, const int* __restrict__ dst,
                              int* __restrict__ cursor2, int* __restrict__ csr, int E) {
    const int s  = blockIdx.x & (NXCD - 1);
    const int lo = s * SLICE_N;
    const int hi = lo + SLICE_N;
    const int stride = (gridDim.x >> 3) * blockDim.x;
    for (int i = (blockIdx.x >> 3) * blockDim.x + threadIdx.x; i < E; i += stride) {
        int d = dst[i];
        if (d >= lo && d < hi) {
            int sv = src[i];
            int g = sv / RNG;
            int p = atomicAdd(&cursor2[d * NG + g], 1);
            csr[p] = sv;
        }
    }
}

// ===========================================================================
// Degree-class ordering, SLICE-LOCAL: bins = [g][dst-slice][class] (g-major,
// 1024 bins). Position space stays g-major ([g*N,(g+1)*N)), but every
// (dst-slice, g) group occupies a CONTIGUOUS position range -> the CSR built
// in permuted layout keeps slice-s writes inside 4 contiguous ~200KB regions
// (XCD-L2-resident), while waves still get 8 equal-degree chains.
// ===========================================================================
__global__ void __launch_bounds__(256)
deg_class_kernel(const int* __restrict__ cnt2, int* __restrict__ dh,
                 int* __restrict__ degT) {
    __shared__ int lh[NBINS];
    const int tid = threadIdx.x;
    for (int i = tid; i < NBINS; i += 256) lh[i] = 0;
    __syncthreads();
    const int n = blockIdx.x * 256 + tid;
    if (n < N_NODES) {
        int4 c4 = *(const int4*)(cnt2 + 4 * n);
        degT[n] = c4.x + c4.y + c4.z + c4.w;
        const int sb = (n / SLICE_N) * 32;
        atomicAdd(&lh[0 * 256 + sb + min(c4.x, 31)], 1);
        atomicAdd(&lh[1 * 256 + sb + min(c4.y, 31)], 1);
        atomicAdd(&lh[2 * 256 + sb + min(c4.z, 31)], 1);
        atomicAdd(&lh[3 * 256 + sb + min(c4.w, 31)], 1);
    }
    __syncthreads();
    for (int i = tid; i < NBINS; i += 256)
        if (lh[i]) atomicAdd(&dh[i], lh[i]);
}

__global__ void __launch_bounds__(NBINS)
scan_deg_kernel(int* __restrict__ dh, int* __restrict__ dcur) {
    __shared__ int tmp[NBINS];
    const int tid = threadIdx.x;
    int v = dh[tid];
    tmp[tid] = v;
    __syncthreads();
    for (int d = 1; d < NBINS; d <<= 1) {
        int t = (tid >= d) ? tmp[tid - d] : 0;
        __syncthreads();
        tmp[tid] += t;
        __syncthreads();
    }
    int excl = tmp[tid] - v;
    dh[tid] = excl;
    dcur[tid] = excl;
}

// ord[p] = node at global position p; posOf[4n+g] = p (inverse permutation)
__global__ void __launch_bounds__(256)
deg_scatter_kernel(const int* __restrict__ cnt2, int* __restrict__ dcur,
                   int* __restrict__ ord, int* __restrict__ posOf) {
    __shared__ int lcnt[NBINS];
    __shared__ int lbase[NBINS];
    __shared__ u16 lrank[1024];
    __shared__ u16 lcls[1024];
    const int tid = threadIdx.x;
    for (int i = tid; i < NBINS; i += 256) lcnt[i] = 0;
    __syncthreads();
    const int n = blockIdx.x * 256 + tid;
    if (n < N_NODES) {
        int4 c4 = *(const int4*)(cnt2 + 4 * n);
        const int sb = (n / SLICE_N) * 32;
        int dg[4] = { c4.x, c4.y, c4.z, c4.w };
#pragma unroll
        for (int g = 0; g < 4; ++g) {
            int c = g * 256 + sb + min(dg[g], 31);
            lcls[tid * 4 + g]  = (u16)c;
            lrank[tid * 4 + g] = (u16)atomicAdd(&lcnt[c], 1);
        }
    }
    __syncthreads();
    for (int i = tid; i < NBINS; i += 256)
        lbase[i] = lcnt[i] ? atomicAdd(&dcur[i], lcnt[i]) : 0;
    __syncthreads();
    if (n < N_NODES) {
#pragma unroll
        for (int g = 0; g < 4; ++g) {
            int c = lcls[tid * 4 + g];
            int p = lbase[c] + lrank[tid * 4 + g];
            ord[p] = n;
            posOf[4 * n + g] = p;
        }
    }
}

// cperm[p] = count of the (n,g) pair living at position p
__global__ void __launch_bounds__(256)
cperm_fill_kernel(const int* __restrict__ ord, const int* __restrict__ cnt2,
                  int* __restrict__ cperm) {
    int p = blockIdx.x * 256 + threadIdx.x;
    if (p < KEYS) {
        int g = p / N_NODES;
        int n = ord[p];
        cperm[p] = cnt2[4 * n + g];
    }
}

// cursor2[key] = offp[posOf[key]]  (CSR is built directly in permuted layout)
__global__ void __launch_bounds__(256)
cursor_init_kernel(const int* __restrict__ offp, const int* __restrict__ posOf,
                   int* __restrict__ cursor2) {
    int k = blockIdx.x * 256 + threadIdx.x;
    if (k < KEYS) cursor2[k] = offp[posOf[k]];
}

// ===========================================================================
// K4: XCD-sliced gather over permuted positions. offp/csr accesses are
// contiguous in position space; 8 chains per wave have equal trip counts.
// Slice (g,h) x-footprint = 25000x128B = 3.2MB (L2). Only the P-row store
// is scattered (full 128B nontemporal line).
// ===========================================================================
__global__ void __launch_bounds__(256)
gatherP_kernel(const float* __restrict__ x, const int* __restrict__ offp,
               const int* __restrict__ csr, const int* __restrict__ ord,
               float* __restrict__ P0, float* __restrict__ P1,
               float* __restrict__ P2, float* __restrict__ P3) {
    const int sid = blockIdx.x & (NXCD - 1);
    const int g = sid >> 1;
    const int h = sid & 1;
    float* __restrict__ P = (g == 0) ? P0 : (g == 1) ? P1 : (g == 2) ? P2 : P3;
    const int chunk = blockIdx.x >> 3;          // < GCH
    const int pos0 = chunk * NPC;
    const int wid  = threadIdx.x >> 6;
    const int lane = threadIdx.x & 63;
    const int r  = lane >> 5;                   // edge parity
    const int cc = lane & 31;                   // channel within half
    const float* __restrict__ xs = x + h * 32 + cc;
    const int* __restrict__ ordg = ord + g * N_NODES;
    const int* __restrict__ offg = offp + g * N_NODES;

    for (int p0 = pos0 + 8 * wid; p0 < pos0 + NPC; p0 += 32) {
        int ni[8], j[8], e[8];
        float s[8];
#pragma unroll
        for (int i = 0; i < 8; ++i) {
            ni[i] = ordg[p0 + i];
            j[i] = offg[p0 + i] + r;
            e[i] = offg[p0 + i + 1];
            s[i] = 0.0f;
        }

        while (true) {
            bool p[8];
            bool any = false;
#pragma unroll
            for (int i = 0; i < 8; ++i) { p[i] = j[i] < e[i]; any = any || p[i]; }
            if (!any) break;

            float t[8];
#pragma unroll
            for (int i = 0; i < 8; ++i) {
                int q = csr[p[i] ? j[i] : 0];
                t[i] = xs[(size_t)q * C];
            }
#pragma unroll
            for (int i = 0; i < 8; ++i) {
                s[i] += p[i] ? t[i] : 0.0f;
                j[i] += 2;
            }
        }

#pragma unroll
        for (int i = 0; i < 8; ++i)
            s[i] += __shfl_xor(s[i], 32);
        if (r == 0) {
#pragma unroll
            for (int i = 0; i < 8; ++i)
                __builtin_nontemporal_store(s[i], &P[(size_t)ni[i] * C + h * 32 + cc]);
        }
    }
}

// ===========================================================================
// K5: GEMM [mean|x](100K x 128) @ [Wl;Wr]^T via mfma_f32_16x16x32_bf16.
// Fused bias+relu+L2norm epilogue. P3 = d_out read-before-write (tile-local).
// ===========================================================================
__global__ void __launch_bounds__(256)
transform_mfma_kernel(const float* __restrict__ x, const int* __restrict__ degT,
                      const float* __restrict__ P0, const float* __restrict__ P1,
                      const float* __restrict__ P2, const float* __restrict__ P3,
                      const float* __restrict__ Wl, const float* __restrict__ bl,
                      const float* __restrict__ Wr, float* __restrict__ out) {
    const int lane = threadIdx.x & 63;
    const int wid  = threadIdx.x >> 6;
    const int col  = lane & 15;
    const int lg   = lane >> 4;

    bf16x8 Bf[4][4];
    float bias[4];
#pragma unroll
    for (int cb = 0; cb < 4; ++cb) {
        const int cc = cb * 16 + col;
        bias[cb] = bl[cc];
#pragma unroll
        for (int ks = 0; ks < 4; ++ks) {
            const int kk0 = ks * 32 + lg * 8;
            const float* W = (kk0 < 64) ? (Wl + (size_t)cc * 64 + kk0)
                                        : (Wr + (size_t)cc * 64 + (kk0 - 64));
            float4 w0 = *(const float4*)W;
            float4 w1 = *(const float4*)(W + 4);
            bf16x8 b;
            b[0]=(short)f2bf(w0.x); b[1]=(short)f2bf(w0.y);
            b[2]=(short)f2bf(w0.z); b[3]=(short)f2bf(w0.w);
            b[4]=(short)f2bf(w1.x); b[5]=(short)f2bf(w1.y);
            b[6]=(short)f2bf(w1.z); b[7]=(short)f2bf(w1.w);
            Bf[cb][ks] = b;
        }
    }

    const int ntiles = N_NODES / 16;
    for (int t = blockIdx.x * 4 + wid; t < ntiles; t += gridDim.x * 4) {
        const int n0 = t * 16;
        const int arow = n0 + col;
        const int deg = degT[arow];
        const float inv = 1.0f / (float)(deg > 1 ? deg : 1);

        f32x4 acc[4];
#pragma unroll
        for (int cb = 0; cb < 4; ++cb) acc[cb] = f32x4{0.f, 0.f, 0.f, 0.f};

#pragma unroll
        for (int ks = 0; ks < 4; ++ks) {
            const int kk0 = ks * 32 + lg * 8;
            bf16x8 a;
            if (kk0 < 64) {
                const float4* p0 = (const float4*)(P0 + (size_t)arow * C + kk0);
                const float4* p1 = (const float4*)(P1 + (size_t)arow * C + kk0);
                const float4* p2 = (const float4*)(P2 + (size_t)arow * C + kk0);
                const float4* p3 = (const float4*)(P3 + (size_t)arow * C + kk0);
                float4 a0 = p0[0], b0 = p1[0], c0 = p2[0], e0 = p3[0];
                float4 a1 = p0[1], b1 = p1[1], c1 = p2[1], e1 = p3[1];
                float s0x = ((a0.x + b0.x) + (c0.x + e0.x)) * inv;
                float s0y = ((a0.y + b0.y) + (c0.y + e0.y)) * inv;
                float s0z = ((a0.z + b0.z) + (c0.z + e0.z)) * inv;
                float s0w = ((a0.w + b0.w) + (c0.w + e0.w)) * inv;
                float s1x = ((a1.x + b1.x) + (c1.x + e1.x)) * inv;
                float s1y = ((a1.y + b1.y) + (c1.y + e1.y)) * inv;
                float s1z = ((a1.z + b1.z) + (c1.z + e1.z)) * inv;
                float s1w = ((a1.w + b1.w) + (c1.w + e1.w)) * inv;
                a[0]=(short)f2bf(s0x); a[1]=(short)f2bf(s0y);
                a[2]=(short)f2bf(s0z); a[3]=(short)f2bf(s0w);
                a[4]=(short)f2bf(s1x); a[5]=(short)f2bf(s1y);
                a[6]=(short)f2bf(s1z); a[7]=(short)f2bf(s1w);
            } else {
                const float4* xp = (const float4*)(x + (size_t)arow * C + (kk0 - 64));
                float4 v0 = xp[0], v1 = xp[1];
                a[0]=(short)f2bf(v0.x); a[1]=(short)f2bf(v0.y);
                a[2]=(short)f2bf(v0.z); a[3]=(short)f2bf(v0.w);
                a[4]=(short)f2bf(v1.x); a[5]=(short)f2bf(v1.y);
                a[6]=(short)f2bf(v1.z); a[7]=(short)f2bf(v1.w);
            }
#pragma unroll
            for (int cb = 0; cb < 4; ++cb)
                acc[cb] = __builtin_amdgcn_mfma_f32_16x16x32_bf16(a, Bf[cb][ks], acc[cb], 0, 0, 0);
        }

#pragma unroll
        for (int jj = 0; jj < 4; ++jj) {
            float v0 = fmaxf(acc[0][jj] + bias[0], 0.0f);
            float v1 = fmaxf(acc[1][jj] + bias[1], 0.0f);
            float v2 = fmaxf(acc[2][jj] + bias[2], 0.0f);
            float v3 = fmaxf(acc[3][jj] + bias[3], 0.0f);
            float sS = (v0 * v0 + v1 * v1) + (v2 * v2 + v3 * v3);
            sS += __shfl_xor(sS, 1);
            sS += __shfl_xor(sS, 2);
            sS += __shfl_xor(sS, 4);
            sS += __shfl_xor(sS, 8);
            float rr = 1.0f / (sqrtf(sS) + EPS);
            const int n = n0 + lg * 4 + jj;
            float* o = out + (size_t)n * C + col;
            o[0]  = v0 * rr;
            o[16] = v1 * rr;
            o[32] = v2 * rr;
            o[48] = v3 * rr;
        }
    }
}

// ===========================================================================
extern "C" void kernel_launch(void* const* d_in, const int* in_sizes, int n_in,
                              void* d_out, int out_size, void* d_ws, size_t ws_size,
                              hipStream_t stream) {
    const float* x    = (const float*)d_in[0];
    const int*   edge = (const int*)d_in[1];
    const float* Wl   = (const float*)d_in[2];
    const float* bl   = (const float*)d_in[3];
    const float* Wr   = (const float*)d_in[4];

    const int E = in_sizes[1] / 2;
    const int* src = edge;
    const int* dst = edge + E;
    const int Epad = (E + 3) & ~3;
    const int bcap = E / NXCD + 32768;

    const size_t nc = (size_t)N_NODES * C;

    // layout: P0 P1 P2 | cnt2 bcur dh dcur degT posOf cursor2 offp bsum
    //         cperm csr ord | bsrc bkey16
    float* P0    = (float*)d_ws;
    float* P1    = P0 + nc;
    float* P2    = P1 + nc;
    int* cnt2    = (int*)(P2 + nc);        // KEYS
    int* bcur    = cnt2 + KEYS;            // 8
    int* dh      = bcur + 8;               // NBINS
    int* dcur    = dh + NBINS;             // NBINS
    int* degT    = dcur + NBINS;           // N
    int* posOf   = degT + N_NODES;         // KEYS
    int* cursor2 = posOf + KEYS;           // KEYS
    int* offp    = cursor2 + KEYS;         // KEYS+4 reserved
    int* bsum    = offp + KEYS + 4;        // 512
    int* cperm   = bsum + 512;             // KEYS
    int* csr     = cperm + KEYS;           // Epad
    int* ord     = csr + Epad;             // KEYS
    int* bsrc    = ord + KEYS;             // 8*bcap
    u16* bkey16  = (u16*)(bsrc + (size_t)8 * bcap);
    float* P3    = (float*)d_out;

    const size_t baseInts = (size_t)KEYS * 6 + 8 + 2 * NBINS + N_NODES + 4 + 512 + Epad;
    const size_t needB = 3ull * nc * 4 + baseInts * 4;
    const size_t needA = needB + (size_t)8 * bcap * 6;

    // zero cnt2 + bcur + dh (adjacent); dcur seeded by scan_deg
    hipMemsetAsync(cnt2, 0, (size_t)(KEYS + 8 + NBINS) * sizeof(int), stream);

    bool tierA = (ws_size >= needA);
    if (tierA) {
        partition_kernel<<<1024, 256, 0, stream>>>(src, dst, bcur, bkey16, bsrc, E, bcap);
        hist2p_kernel<<<NXCD * 96, 256, 0, stream>>>(bcur, bkey16, cnt2, bcap);
    } else {
        hist2_kernel<<<NXCD * 256, 256, 0, stream>>>(src, dst, cnt2, E);
    }

    // slice-local degree-class ordering + permuted scan
    deg_class_kernel<<<NDH, 256, 0, stream>>>(cnt2, dh, degT);
    scan_deg_kernel<<<1, NBINS, 0, stream>>>(dh, dcur);
    deg_scatter_kernel<<<NDH, 256, 0, stream>>>(cnt2, dcur, ord, posOf);
    cperm_fill_kernel<<<(KEYS + 255) / 256, 256, 0, stream>>>(ord, cnt2, cperm);
    scan_block_kernel<<<NBLKK, SCAN_BLK, 0, stream>>>(cperm, offp, bsum, KEYS);
    scan_bsum_kernel<<<1, 512, 0, stream>>>(bsum, NBLKK);
    scan_add_kernel<<<NBLKK, SCAN_BLK, 0, stream>>>(offp, bsum, KEYS, E);
    cursor_init_kernel<<<(KEYS + 255) / 256, 256, 0, stream>>>(offp, posOf, cursor2);

    if (tierA) {
        build2p_kernel<<<NXCD * 96, 256, 0, stream>>>(bcur, bkey16, bsrc, cursor2, csr, bcap);
    } else {
        build2_kernel<<<NXCD * 256, 256, 0, stream>>>(src, dst, cursor2, csr, E);
    }

    gatherP_kernel<<<NXCD * GCH, 256, 0, stream>>>(x, offp, csr, ord, P0, P1, P2, P3);
    transform_mfma_kernel<<<1024, 256, 0, stream>>>(x, degT, P0, P1, P2, P3,
                                                    Wl, bl, Wr, (float*)d_out);
}

// Round 10
// 317.670 us; speedup vs baseline: 1.0592x; 1.0402x over previous
//
#include <hip/hip_runtime.h>
#include <math.h>

#define N_NODES 100000
#define C 64
#define EPS 1e-9f
#define SCAN_BLK 1024
#define NXCD 8
#define NG 4
#define RNG (N_NODES / NG)            // 25000 src rows per g-bucket
#define SLICE_N (N_NODES / NXCD)      // 12500 dst rows per slice
#define KEYS (N_NODES * NG)           // 400000 (dst,g) keys == position count
#define NBLKK ((KEYS + SCAN_BLK - 1) / SCAN_BLK)   // 391
#define GCH 500
#define GPB 25                        // groups per block (GCH*GPB*8 == N_NODES)
#define NDH ((N_NODES + 255) / 256)   // 391 blocks for per-node kernels
#define NBINS 1024                    // [g][dst-slice][class] = 4*8*32

typedef __attribute__((ext_vector_type(8))) short bf16x8;
typedef __attribute__((ext_vector_type(4))) float f32x4;
typedef unsigned short u16;
typedef unsigned char u8;

__device__ __forceinline__ unsigned short f2bf(float f) {
    union { float f; unsigned int u; } v; v.f = f;
    unsigned int u = v.u;
    return (unsigned short)((u + 0x7FFFu + ((u >> 16) & 1u)) >> 16);
}

// ===========================================================================
// Generic scan kernels
// ===========================================================================
__global__ void scan_block_kernel(const int* __restrict__ cnt, int* __restrict__ off,
                                  int* __restrict__ bsum, int n) {
    __shared__ int tmp[SCAN_BLK];
    int tid = threadIdx.x;
    int gid = blockIdx.x * SCAN_BLK + tid;
    int v = (gid < n) ? cnt[gid] : 0;
    tmp[tid] = v;
    __syncthreads();
    for (int d = 1; d < SCAN_BLK; d <<= 1) {
        int t = (tid >= d) ? tmp[tid - d] : 0;
        __syncthreads();
        tmp[tid] += t;
        __syncthreads();
    }
    if (gid < n) off[gid] = tmp[tid] - v;
    if (tid == SCAN_BLK - 1) bsum[blockIdx.x] = tmp[tid];
}

__global__ void scan_bsum_kernel(int* __restrict__ bsum, int nb) {
    __shared__ int tmp[512];
    int tid = threadIdx.x;
    int v = (tid < nb) ? bsum[tid] : 0;
    tmp[tid] = v;
    __syncthreads();
    for (int d = 1; d < 512; d <<= 1) {
        int t = (tid >= d) ? tmp[tid - d] : 0;
        __syncthreads();
        tmp[tid] += t;
        __syncthreads();
    }
    if (tid < nb) bsum[tid] = tmp[tid] - v;
}

__global__ void scan_add_kernel(int* __restrict__ off, const int* __restrict__ bsum,
                                int n, int E) {
    int gid = blockIdx.x * SCAN_BLK + threadIdx.x;
    if (gid < n) off[gid] += bsum[blockIdx.x];
    if (gid == 0) off[n] = E;
}

// ===========================================================================
// K0: partition edges into 8 dst-range buckets (per-slice (key16,src) arrays)
// ===========================================================================
__global__ void __launch_bounds__(256)
partition_kernel(const int* __restrict__ src, const int* __restrict__ dst,
                 int* __restrict__ bcur, u16* __restrict__ bkey16,
                 int* __restrict__ bsrc, int E, int bcap) {
    __shared__ int lcnt[NXCD];
    __shared__ int lbase[NXCD];
    const int tid = threadIdx.x;
    const int per = (E + gridDim.x - 1) / gridDim.x;
    const int i0 = blockIdx.x * per;
    const int i1 = min(i0 + per, E);

    if (tid < NXCD) lcnt[tid] = 0;
    __syncthreads();
    for (int i = i0 + tid; i < i1; i += 256)
        atomicAdd(&lcnt[dst[i] / SLICE_N], 1);
    __syncthreads();
    if (tid < NXCD) {
        lbase[tid] = atomicAdd(&bcur[tid], lcnt[tid]);
        lcnt[tid] = 0;
    }
    __syncthreads();
    for (int i = i0 + tid; i < i1; i += 256) {
        int d  = dst[i];
        int sv = src[i];
        int s  = d / SLICE_N;
        int p  = lbase[s] + atomicAdd(&lcnt[s], 1);
        size_t pos = (size_t)s * bcap + p;
        bkey16[pos] = (u16)((d - s * SLICE_N) * NG + sv / RNG);
        bsrc[pos] = sv;
    }
}

// hist over bucketed keys; slice-s atomics stay in a 200KB XCD-local region.
__global__ void hist2p_kernel(const int* __restrict__ bcur,
                              const u16* __restrict__ bkey16,
                              int* __restrict__ cnt2, int bcap) {
    const int s = blockIdx.x & (NXCD - 1);
    const int bn = bcur[s];
    const u16* __restrict__ k = bkey16 + (size_t)s * bcap;
    int* __restrict__ c2 = cnt2 + s * (SLICE_N * NG);
    const int stride = (gridDim.x >> 3) * blockDim.x;
    for (int i = (blockIdx.x >> 3) * blockDim.x + threadIdx.x; i < bn; i += stride)
        atomicAdd(&c2[k[i]], 1);
}

// tag each bucketed element with its key's degree class (cnt2 is final here)
__global__ void __launch_bounds__(256)
class_tag_kernel(const int* __restrict__ bcur, const u16* __restrict__ bkey16,
                 const int* __restrict__ cnt2, u8* __restrict__ bcls, int bcap) {
    const int s = blockIdx.x & (NXCD - 1);
    const int bn = bcur[s];
    const u16* __restrict__ k = bkey16 + (size_t)s * bcap;
    const int* __restrict__ c2 = cnt2 + s * (SLICE_N * NG);
    u8* __restrict__ cl = bcls + (size_t)s * bcap;
    const int stride = (gridDim.x >> 3) * blockDim.x;
    for (int i = (blockIdx.x >> 3) * blockDim.x + threadIdx.x; i < bn; i += stride)
        cl[i] = (u8)min(c2[k[i]], 31);
}

// time-blocked build pass: only keys whose class is in [clo,chi) are placed.
// The permuted csr layout is contiguous by (g,slice,class) -> this pass's
// writes land in a ~200KB contiguous active region per slice (full lines
// complete before eviction; kills the 10x write amplification).
__global__ void __launch_bounds__(256)
build_pass_kernel(const int* __restrict__ bcur, const u16* __restrict__ bkey16,
                  const u8* __restrict__ bcls, const int* __restrict__ bsrc,
                  int* __restrict__ cursor2, int* __restrict__ csr,
                  int bcap, int clo, int chi) {
    const int s = blockIdx.x & (NXCD - 1);
    const int bn = bcur[s];
    const u16* __restrict__ k  = bkey16 + (size_t)s * bcap;
    const u8*  __restrict__ cl = bcls + (size_t)s * bcap;
    const int* __restrict__ sv = bsrc + (size_t)s * bcap;
    int* __restrict__ cur = cursor2 + s * (SLICE_N * NG);
    const int stride = (gridDim.x >> 3) * blockDim.x;
    for (int i = (blockIdx.x >> 3) * blockDim.x + threadIdx.x; i < bn; i += stride) {
        int c = cl[i];
        if (c >= clo && c < chi) {
            int p = atomicAdd(&cur[k[i]], 1);
            csr[p] = sv[i];
        }
    }
}

// Tier-B hist/build (no bucket arrays): direct 8x edge-list streaming
__global__ void hist2_kernel(const int* __restrict__ src, const int* __restrict__ dst,
                             int* __restrict__ cnt2, int E) {
    const int s  = blockIdx.x & (NXCD - 1);
    const int lo = s * SLICE_N;
    const int hi = lo + SLICE_N;
    const int stride = (gridDim.x >> 3) * blockDim.x;
    for (int i = (blockIdx.x >> 3) * blockDim.x + threadIdx.x; i < E; i += stride) {
        int d = dst[i];
        if (d >= lo && d < hi) {
            int g = src[i] / RNG;
            atomicAdd(&cnt2[d * NG + g], 1);
        }
    }
}

__global__ void build2_kernel(const int* __restrict__ src, const int* __restrict__ dst,
                              int* __restrict__ cursor2, int* __restrict__ csr, int E) {
    const int s  = blockIdx.x & (NXCD - 1);
    const int lo = s * SLICE_N;
    const int hi = lo + SLICE_N;
    const int stride = (gridDim.x >> 3) * blockDim.x;
    for (int i = (blockIdx.x >> 3) * blockDim.x + threadIdx.x; i < E; i += stride) {
        int d = dst[i];
        if (d >= lo && d < hi) {
            int sv = src[i];
            int g = sv / RNG;
            int p = atomicAdd(&cursor2[d * NG + g], 1);
            csr[p] = sv;
        }
    }
}

// ===========================================================================
// Slice-local degree-class ordering: bins = [g][dst-slice][class] (g-major,
// 1024 bins). Position space stays g-major; every (dst-slice,g) group is a
// contiguous position range (XCD-local csr writes) and positions within it
// are class-sorted (equal chains per gather wave).
// ===========================================================================
__global__ void __launch_bounds__(256)
deg_class_kernel(const int* __restrict__ cnt2, int* __restrict__ dh,
                 int* __restrict__ degT) {
    __shared__ int lh[NBINS];
    const int tid = threadIdx.x;
    for (int i = tid; i < NBINS; i += 256) lh[i] = 0;
    __syncthreads();
    const int n = blockIdx.x * 256 + tid;
    if (n < N_NODES) {
        int4 c4 = *(const int4*)(cnt2 + 4 * n);
        degT[n] = c4.x + c4.y + c4.z + c4.w;
        const int sb = (n / SLICE_N) * 32;
        atomicAdd(&lh[0 * 256 + sb + min(c4.x, 31)], 1);
        atomicAdd(&lh[1 * 256 + sb + min(c4.y, 31)], 1);
        atomicAdd(&lh[2 * 256 + sb + min(c4.z, 31)], 1);
        atomicAdd(&lh[3 * 256 + sb + min(c4.w, 31)], 1);
    }
    __syncthreads();
    for (int i = tid; i < NBINS; i += 256)
        if (lh[i]) atomicAdd(&dh[i], lh[i]);
}

__global__ void __launch_bounds__(NBINS)
scan_deg_kernel(int* __restrict__ dh, int* __restrict__ dcur) {
    __shared__ int tmp[NBINS];
    const int tid = threadIdx.x;
    int v = dh[tid];
    tmp[tid] = v;
    __syncthreads();
    for (int d = 1; d < NBINS; d <<= 1) {
        int t = (tid >= d) ? tmp[tid - d] : 0;
        __syncthreads();
        tmp[tid] += t;
        __syncthreads();
    }
    int excl = tmp[tid] - v;
    dh[tid] = excl;
    dcur[tid] = excl;
}

// ord[p] = node at global position p; posOf[4n+g] = p (inverse permutation)
__global__ void __launch_bounds__(256)
deg_scatter_kernel(const int* __restrict__ cnt2, int* __restrict__ dcur,
                   int* __restrict__ ord, int* __restrict__ posOf) {
    __shared__ int lcnt[NBINS];
    __shared__ int lbase[NBINS];
    __shared__ u16 lrank[1024];
    __shared__ u16 lcls[1024];
    const int tid = threadIdx.x;
    for (int i = tid; i < NBINS; i += 256) lcnt[i] = 0;
    __syncthreads();
    const int n = blockIdx.x * 256 + tid;
    if (n < N_NODES) {
        int4 c4 = *(const int4*)(cnt2 + 4 * n);
        const int sb = (n / SLICE_N) * 32;
        int dg[4] = { c4.x, c4.y, c4.z, c4.w };
#pragma unroll
        for (int g = 0; g < 4; ++g) {
            int c = g * 256 + sb + min(dg[g], 31);
            lcls[tid * 4 + g]  = (u16)c;
            lrank[tid * 4 + g] = (u16)atomicAdd(&lcnt[c], 1);
        }
    }
    __syncthreads();
    for (int i = tid; i < NBINS; i += 256)
        lbase[i] = lcnt[i] ? atomicAdd(&dcur[i], lcnt[i]) : 0;
    __syncthreads();
    if (n < N_NODES) {
#pragma unroll
        for (int g = 0; g < 4; ++g) {
            int c = lcls[tid * 4 + g];
            int p = lbase[c] + lrank[tid * 4 + g];
            ord[p] = n;
            posOf[4 * n + g] = p;
        }
    }
}

// cperm[p] = count of the (n,g) pair living at position p
__global__ void __launch_bounds__(256)
cperm_fill_kernel(const int* __restrict__ ord, const int* __restrict__ cnt2,
                  int* __restrict__ cperm) {
    int p = blockIdx.x * 256 + threadIdx.x;
    if (p < KEYS) {
        int g = p / N_NODES;
        int n = ord[p];
        cperm[p] = cnt2[4 * n + g];
    }
}

// cursor2[key] = offp[posOf[key]]  (CSR is built directly in permuted layout)
__global__ void __launch_bounds__(256)
cursor_init_kernel(const int* __restrict__ offp, const int* __restrict__ posOf,
                   int* __restrict__ cursor2) {
    int k = blockIdx.x * 256 + threadIdx.x;
    if (k < KEYS) cursor2[k] = offp[posOf[k]];
}

// ===========================================================================
// K4: XCD-sliced gather over permuted positions, STRIDED group assignment:
// block `chunk` takes groups {chunk + gi*GCH} -> uniform class mix per block
// (no straggler tail), while each group is 8 consecutive same-class positions
// (equal chains, contiguous offp/ord reads, full-line P store).
// ===========================================================================
__global__ void __launch_bounds__(256)
gatherP_kernel(const float* __restrict__ x, const int* __restrict__ offp,
               const int* __restrict__ csr, const int* __restrict__ ord,
               float* __restrict__ P0, float* __restrict__ P1,
               float* __restrict__ P2, float* __restrict__ P3) {
    const int sid = blockIdx.x & (NXCD - 1);
    const int g = sid >> 1;
    const int h = sid & 1;
    float* __restrict__ P = (g == 0) ? P0 : (g == 1) ? P1 : (g == 2) ? P2 : P3;
    const int chunk = blockIdx.x >> 3;          // < GCH
    const int wid  = threadIdx.x >> 6;
    const int lane = threadIdx.x & 63;
    const int r  = lane >> 5;                   // edge parity
    const int cc = lane & 31;                   // channel within half
    const float* __restrict__ xs = x + h * 32 + cc;
    const int* __restrict__ ordg = ord + g * N_NODES;
    const int* __restrict__ offg = offp + g * N_NODES;

    for (int gi = wid; gi < GPB; gi += 4) {
        const int p0 = (chunk + gi * GCH) * 8;
        int ni[8], j[8], e[8];
        float s[8];
#pragma unroll
        for (int i = 0; i < 8; ++i) {
            ni[i] = ordg[p0 + i];
            j[i] = offg[p0 + i] + r;
            e[i] = offg[p0 + i + 1];
            s[i] = 0.0f;
        }

        while (true) {
            bool p[8];
            bool any = false;
#pragma unroll
            for (int i = 0; i < 8; ++i) { p[i] = j[i] < e[i]; any = any || p[i]; }
            if (!any) break;

            float t[8];
#pragma unroll
            for (int i = 0; i < 8; ++i) {
                int q = csr[p[i] ? j[i] : 0];
                t[i] = xs[(size_t)q * C];
            }
#pragma unroll
            for (int i = 0; i < 8; ++i) {
                s[i] += p[i] ? t[i] : 0.0f;
                j[i] += 2;
            }
        }

#pragma unroll
        for (int i = 0; i < 8; ++i)
            s[i] += __shfl_xor(s[i], 32);
        if (r == 0) {
#pragma unroll
            for (int i = 0; i < 8; ++i)
                __builtin_nontemporal_store(s[i], &P[(size_t)ni[i] * C + h * 32 + cc]);
        }
    }
}

// ===========================================================================
// K5: GEMM [mean|x](100K x 128) @ [Wl;Wr]^T via mfma_f32_16x16x32_bf16.
// Fused bias+relu+L2norm epilogue. P3 = d_out read-before-write (tile-local).
// ===========================================================================
__global__ void __launch_bounds__(256)
transform_mfma_kernel(const float* __restrict__ x, const int* __restrict__ degT,
                      const float* __restrict__ P0, const float* __restrict__ P1,
                      const float* __restrict__ P2, const float* __restrict__ P3,
                      const float* __restrict__ Wl, const float* __restrict__ bl,
                      const float* __restrict__ Wr, float* __restrict__ out) {
    const int lane = threadIdx.x & 63;
    const int wid  = threadIdx.x >> 6;
    const int col  = lane & 15;
    const int lg   = lane >> 4;

    bf16x8 Bf[4][4];
    float bias[4];
#pragma unroll
    for (int cb = 0; cb < 4; ++cb) {
        const int cc = cb * 16 + col;
        bias[cb] = bl[cc];
#pragma unroll
        for (int ks = 0; ks < 4; ++ks) {
            const int kk0 = ks * 32 + lg * 8;
            const float* W = (kk0 < 64) ? (Wl + (size_t)cc * 64 + kk0)
                                        : (Wr + (size_t)cc * 64 + (kk0 - 64));
            float4 w0 = *(const float4*)W;
            float4 w1 = *(const float4*)(W + 4);
            bf16x8 b;
            b[0]=(short)f2bf(w0.x); b[1]=(short)f2bf(w0.y);
            b[2]=(short)f2bf(w0.z); b[3]=(short)f2bf(w0.w);
            b[4]=(short)f2bf(w1.x); b[5]=(short)f2bf(w1.y);
            b[6]=(short)f2bf(w1.z); b[7]=(short)f2bf(w1.w);
            Bf[cb][ks] = b;
        }
    }

    const int ntiles = N_NODES / 16;
    for (int t = blockIdx.x * 4 + wid; t < ntiles; t += gridDim.x * 4) {
        const int n0 = t * 16;
        const int arow = n0 + col;
        const int deg = degT[arow];
        const float inv = 1.0f / (float)(deg > 1 ? deg : 1);

        f32x4 acc[4];
#pragma unroll
        for (int cb = 0; cb < 4; ++cb) acc[cb] = f32x4{0.f, 0.f, 0.f, 0.f};

#pragma unroll
        for (int ks = 0; ks < 4; ++ks) {
            const int kk0 = ks * 32 + lg * 8;
            bf16x8 a;
            if (kk0 < 64) {
                const float4* p0 = (const float4*)(P0 + (size_t)arow * C + kk0);
                const float4* p1 = (const float4*)(P1 + (size_t)arow * C + kk0);
                const float4* p2 = (const float4*)(P2 + (size_t)arow * C + kk0);
                const float4* p3 = (const float4*)(P3 + (size_t)arow * C + kk0);
                float4 a0 = p0[0], b0 = p1[0], c0 = p2[0], e0 = p3[0];
                float4 a1 = p0[1], b1 = p1[1], c1 = p2[1], e1 = p3[1];
                float s0x = ((a0.x + b0.x) + (c0.x + e0.x)) * inv;
                float s0y = ((a0.y + b0.y) + (c0.y + e0.y)) * inv;
                float s0z = ((a0.z + b0.z) + (c0.z + e0.z)) * inv;
                float s0w = ((a0.w + b0.w) + (c0.w + e0.w)) * inv;
                float s1x = ((a1.x + b1.x) + (c1.x + e1.x)) * inv;
                float s1y = ((a1.y + b1.y) + (c1.y + e1.y)) * inv;
                float s1z = ((a1.z + b1.z) + (c1.z + e1.z)) * inv;
                float s1w = ((a1.w + b1.w) + (c1.w + e1.w)) * inv;
                a[0]=(short)f2bf(s0x); a[1]=(short)f2bf(s0y);
                a[2]=(short)f2bf(s0z); a[3]=(short)f2bf(s0w);
                a[4]=(short)f2bf(s1x); a[5]=(short)f2bf(s1y);
                a[6]=(short)f2bf(s1z); a[7]=(short)f2bf(s1w);
            } else {
                const float4* xp = (const float4*)(x + (size_t)arow * C + (kk0 - 64));
                float4 v0 = xp[0], v1 = xp[1];
                a[0]=(short)f2bf(v0.x); a[1]=(short)f2bf(v0.y);
                a[2]=(short)f2bf(v0.z); a[3]=(short)f2bf(v0.w);
                a[4]=(short)f2bf(v1.x); a[5]=(short)f2bf(v1.y);
                a[6]=(short)f2bf(v1.z); a[7]=(short)f2bf(v1.w);
            }
#pragma unroll
            for (int cb = 0; cb < 4; ++cb)
                acc[cb] = __builtin_amdgcn_mfma_f32_16x16x32_bf16(a, Bf[cb][ks], acc[cb], 0, 0, 0);
        }

#pragma unroll
        for (int jj = 0; jj < 4; ++jj) {
            float v0 = fmaxf(acc[0][jj] + bias[0], 0.0f);
            float v1 = fmaxf(acc[1][jj] + bias[1], 0.0f);
            float v2 = fmaxf(acc[2][jj] + bias[2], 0.0f);
            float v3 = fmaxf(acc[3][jj] + bias[3], 0.0f);
            float sS = (v0 * v0 + v1 * v1) + (v2 * v2 + v3 * v3);
            sS += __shfl_xor(sS, 1);
            sS += __shfl_xor(sS, 2);
            sS += __shfl_xor(sS, 4);
            sS += __shfl_xor(sS, 8);
            float rr = 1.0f / (sqrtf(sS) + EPS);
            const int n = n0 + lg * 4 + jj;
            float* o = out + (size_t)n * C + col;
            o[0]  = v0 * rr;
            o[16] = v1 * rr;
            o[32] = v2 * rr;
            o[48] = v3 * rr;
        }
    }
}

// ===========================================================================
extern "C" void kernel_launch(void* const* d_in, const int* in_sizes, int n_in,
                              void* d_out, int out_size, void* d_ws, size_t ws_size,
                              hipStream_t stream) {
    const float* x    = (const float*)d_in[0];
    const int*   edge = (const int*)d_in[1];
    const float* Wl   = (const float*)d_in[2];
    const float* bl   = (const float*)d_in[3];
    const float* Wr   = (const float*)d_in[4];

    const int E = in_sizes[1] / 2;
    const int* src = edge;
    const int* dst = edge + E;
    const int Epad = (E + 3) & ~3;
    const int bcap = E / NXCD + 32768;

    const size_t nc = (size_t)N_NODES * C;

    // layout: P0 P1 P2 | cnt2 bcur dh dcur degT posOf cursor2 offp bsum
    //         cperm csr ord | bsrc bkey16 bcls
    float* P0    = (float*)d_ws;
    float* P1    = P0 + nc;
    float* P2    = P1 + nc;
    int* cnt2    = (int*)(P2 + nc);        // KEYS
    int* bcur    = cnt2 + KEYS;            // 8
    int* dh      = bcur + 8;               // NBINS
    int* dcur    = dh + NBINS;             // NBINS
    int* degT    = dcur + NBINS;           // N
    int* posOf   = degT + N_NODES;         // KEYS
    int* cursor2 = posOf + KEYS;           // KEYS
    int* offp    = cursor2 + KEYS;         // KEYS+4 reserved
    int* bsum    = offp + KEYS + 4;        // 512
    int* cperm   = bsum + 512;             // KEYS
    int* csr     = cperm + KEYS;           // Epad
    int* ord     = csr + Epad;             // KEYS
    int* bsrc    = ord + KEYS;             // 8*bcap
    u16* bkey16  = (u16*)(bsrc + (size_t)8 * bcap);
    u8*  bcls    = (u8*)(bkey16 + (size_t)8 * bcap);
    float* P3    = (float*)d_out;

    const size_t baseInts = (size_t)KEYS * 6 + 8 + 2 * NBINS + N_NODES + 4 + 512 + Epad;
    const size_t needB = 3ull * nc * 4 + baseInts * 4;
    const size_t needA = needB + (size_t)8 * bcap * 7;

    // zero cnt2 + bcur + dh (adjacent); dcur seeded by scan_deg
    hipMemsetAsync(cnt2, 0, (size_t)(KEYS + 8 + NBINS) * sizeof(int), stream);

    bool tierA = (ws_size >= needA);
    if (tierA) {
        partition_kernel<<<1024, 256, 0, stream>>>(src, dst, bcur, bkey16, bsrc, E, bcap);
        hist2p_kernel<<<NXCD * 256, 256, 0, stream>>>(bcur, bkey16, cnt2, bcap);
    } else {
        hist2_kernel<<<NXCD * 256, 256, 0, stream>>>(src, dst, cnt2, E);
    }

    // slice-local degree-class ordering + permuted scan
    deg_class_kernel<<<NDH, 256, 0, stream>>>(cnt2, dh, degT);
    scan_deg_kernel<<<1, NBINS, 0, stream>>>(dh, dcur);
    deg_scatter_kernel<<<NDH, 256, 0, stream>>>(cnt2, dcur, ord, posOf);
    cperm_fill_kernel<<<(KEYS + 255) / 256, 256, 0, stream>>>(ord, cnt2, cperm);
    scan_block_kernel<<<NBLKK, SCAN_BLK, 0, stream>>>(cperm, offp, bsum, KEYS);
    scan_bsum_kernel<<<1, 512, 0, stream>>>(bsum, NBLKK);
    scan_add_kernel<<<NBLKK, SCAN_BLK, 0, stream>>>(offp, bsum, KEYS, E);
    cursor_init_kernel<<<(KEYS + 255) / 256, 256, 0, stream>>>(offp, posOf, cursor2);

    if (tierA) {
        class_tag_kernel<<<NXCD * 256, 256, 0, stream>>>(bcur, bkey16, cnt2, bcls, bcap);
        // time-blocked build: 4 class-range passes (device-ordered via stream)
        build_pass_kernel<<<NXCD * 256, 256, 0, stream>>>(bcur, bkey16, bcls, bsrc,
                                                          cursor2, csr, bcap, 0, 4);
        build_pass_kernel<<<NXCD * 256, 256, 0, stream>>>(bcur, bkey16, bcls, bsrc,
                                                          cursor2, csr, bcap, 4, 5);
        build_pass_kernel<<<NXCD * 256, 256, 0, stream>>>(bcur, bkey16, bcls, bsrc,
                                                          cursor2, csr, bcap, 5, 7);
        build_pass_kernel<<<NXCD * 256, 256, 0, stream>>>(bcur, bkey16, bcls, bsrc,
                                                          cursor2, csr, bcap, 7, 32);
    } else {
        build2_kernel<<<NXCD * 256, 256, 0, stream>>>(src, dst, cursor2, csr, E);
    }

    gatherP_kernel<<<NXCD * GCH, 256, 0, stream>>>(x, offp, csr, ord, P0, P1, P2, P3);
    transform_mfma_kernel<<<1024, 256, 0, stream>>>(x, degT, P0, P1, P2, P3,
                                                    Wl, bl, Wr, (float*)d_out);
}

// Round 11
// 308.894 us; speedup vs baseline: 1.0893x; 1.0284x over previous
//
#include <hip/hip_runtime.h>
#include <math.h>

#define N_NODES 100000
#define C 64
#define EPS 1e-9f
#define SCAN_BLK 1024
#define NXCD 8
#define NG 4
#define RNG (N_NODES / NG)            // 25000 src rows per g-bucket
#define SLICE_N (N_NODES / NXCD)      // 12500 dst rows per slice
#define KEYS (N_NODES * NG)           // 400000 (dst,g) keys == position count
#define NBLKK ((KEYS + SCAN_BLK - 1) / SCAN_BLK)   // 391
#define GCH 500
#define GPB 25                        // groups per block (GCH*GPB*8 == N_NODES)
#define NDH ((N_NODES + 255) / 256)   // 391 blocks for per-node kernels
#define NBINS 1024                    // [g][dst-slice][class] = 4*8*32

typedef __attribute__((ext_vector_type(8))) short bf16x8;
typedef __attribute__((ext_vector_type(4))) float f32x4;
typedef unsigned short u16;

__device__ __forceinline__ unsigned short f2bf(float f) {
    union { float f; unsigned int u; } v; v.f = f;
    unsigned int u = v.u;
    return (unsigned short)((u + 0x7FFFu + ((u >> 16) & 1u)) >> 16);
}

// ===========================================================================
// Scan kernels. scan_block_perm reads the per-position count on the fly:
// cperm[p] = cnt2[4*ord[p] + p/N]  (fuses the old cperm_fill kernel).
// ===========================================================================
__global__ void scan_block_perm_kernel(const int* __restrict__ ord,
                                       const int* __restrict__ cnt2,
                                       int* __restrict__ off,
                                       int* __restrict__ bsum, int n) {
    __shared__ int tmp[SCAN_BLK];
    int tid = threadIdx.x;
    int gid = blockIdx.x * SCAN_BLK + tid;
    int v = 0;
    if (gid < n) {
        int g = gid / N_NODES;
        v = cnt2[4 * ord[gid] + g];
    }
    tmp[tid] = v;
    __syncthreads();
    for (int d = 1; d < SCAN_BLK; d <<= 1) {
        int t = (tid >= d) ? tmp[tid - d] : 0;
        __syncthreads();
        tmp[tid] += t;
        __syncthreads();
    }
    if (gid < n) off[gid] = tmp[tid] - v;
    if (tid == SCAN_BLK - 1) bsum[blockIdx.x] = tmp[tid];
}

__global__ void scan_bsum_kernel(int* __restrict__ bsum, int nb) {
    __shared__ int tmp[512];
    int tid = threadIdx.x;
    int v = (tid < nb) ? bsum[tid] : 0;
    tmp[tid] = v;
    __syncthreads();
    for (int d = 1; d < 512; d <<= 1) {
        int t = (tid >= d) ? tmp[tid - d] : 0;
        __syncthreads();
        tmp[tid] += t;
        __syncthreads();
    }
    if (tid < nb) bsum[tid] = tmp[tid] - v;
}

__global__ void scan_add_kernel(int* __restrict__ off, const int* __restrict__ bsum,
                                int n, int E) {
    int gid = blockIdx.x * SCAN_BLK + threadIdx.x;
    if (gid < n) off[gid] += bsum[blockIdx.x];
    if (gid == 0) off[n] = E;
}

// ===========================================================================
// K0: partition edges into 8 dst-range buckets (per-slice (key16,src) arrays)
// ===========================================================================
__global__ void __launch_bounds__(256)
partition_kernel(const int* __restrict__ src, const int* __restrict__ dst,
                 int* __restrict__ bcur, u16* __restrict__ bkey16,
                 int* __restrict__ bsrc, int E, int bcap) {
    __shared__ int lcnt[NXCD];
    __shared__ int lbase[NXCD];
    const int tid = threadIdx.x;
    const int per = (E + gridDim.x - 1) / gridDim.x;
    const int i0 = blockIdx.x * per;
    const int i1 = min(i0 + per, E);

    if (tid < NXCD) lcnt[tid] = 0;
    __syncthreads();
    for (int i = i0 + tid; i < i1; i += 256)
        atomicAdd(&lcnt[dst[i] / SLICE_N], 1);
    __syncthreads();
    if (tid < NXCD) {
        lbase[tid] = atomicAdd(&bcur[tid], lcnt[tid]);
        lcnt[tid] = 0;
    }
    __syncthreads();
    for (int i = i0 + tid; i < i1; i += 256) {
        int d  = dst[i];
        int sv = src[i];
        int s  = d / SLICE_N;
        int p  = lbase[s] + atomicAdd(&lcnt[s], 1);
        size_t pos = (size_t)s * bcap + p;
        bkey16[pos] = (u16)((d - s * SLICE_N) * NG + sv / RNG);
        bsrc[pos] = sv;
    }
}

// hist over bucketed keys; slice-s atomics stay in a 200KB XCD-local region.
__global__ void hist2p_kernel(const int* __restrict__ bcur,
                              const u16* __restrict__ bkey16,
                              int* __restrict__ cnt2, int bcap) {
    const int s = blockIdx.x & (NXCD - 1);
    const int bn = bcur[s];
    const u16* __restrict__ k = bkey16 + (size_t)s * bcap;
    int* __restrict__ c2 = cnt2 + s * (SLICE_N * NG);
    const int stride = (gridDim.x >> 3) * blockDim.x;
    for (int i = (blockIdx.x >> 3) * blockDim.x + threadIdx.x; i < bn; i += stride)
        atomicAdd(&c2[k[i]], 1);
}

// time-blocked build pass: only keys whose degree class is in [clo,chi) are
// placed; class read directly from XCD-local cnt2 (no tag array). Permuted
// csr layout is contiguous by (g,slice,class) -> each pass's writes fall in a
// small contiguous active region (full lines complete before eviction).
__global__ void __launch_bounds__(256)
build_pass_kernel(const int* __restrict__ bcur, const u16* __restrict__ bkey16,
                  const int* __restrict__ bsrc, const int* __restrict__ cnt2,
                  int* __restrict__ cursor2, int* __restrict__ csr,
                  int bcap, int clo, int chi) {
    const int s = blockIdx.x & (NXCD - 1);
    const int bn = bcur[s];
    const u16* __restrict__ k  = bkey16 + (size_t)s * bcap;
    const int* __restrict__ sv = bsrc + (size_t)s * bcap;
    const int* __restrict__ c2 = cnt2 + s * (SLICE_N * NG);
    int* __restrict__ cur = cursor2 + s * (SLICE_N * NG);
    const int stride = (gridDim.x >> 3) * blockDim.x;
    for (int i = (blockIdx.x >> 3) * blockDim.x + threadIdx.x; i < bn; i += stride) {
        int kk = k[i];
        int c = min(c2[kk], 31);
        if (c >= clo && c < chi) {
            int p = atomicAdd(&cur[kk], 1);
            csr[p] = sv[i];
        }
    }
}

// Tier-B hist/build (no bucket arrays): direct 8x edge-list streaming
__global__ void hist2_kernel(const int* __restrict__ src, const int* __restrict__ dst,
                             int* __restrict__ cnt2, int E) {
    const int s  = blockIdx.x & (NXCD - 1);
    const int lo = s * SLICE_N;
    const int hi = lo + SLICE_N;
    const int stride = (gridDim.x >> 3) * blockDim.x;
    for (int i = (blockIdx.x >> 3) * blockDim.x + threadIdx.x; i < E; i += stride) {
        int d = dst[i];
        if (d >= lo && d < hi) {
            int g = src[i] / RNG;
            atomicAdd(&cnt2[d * NG + g], 1);
        }
    }
}

__global__ void build2_kernel(const int* __restrict__ src, const int* __restrict__ dst,
                              int* __restrict__ cursor2, int* __restrict__ csr, int E) {
    const int s  = blockIdx.x & (NXCD - 1);
    const int lo = s * SLICE_N;
    const int hi = lo + SLICE_N;
    const int stride = (gridDim.x >> 3) * blockDim.x;
    for (int i = (blockIdx.x >> 3) * blockDim.x + threadIdx.x; i < E; i += stride) {
        int d = dst[i];
        if (d >= lo && d < hi) {
            int sv = src[i];
            int g = sv / RNG;
            int p = atomicAdd(&cursor2[d * NG + g], 1);
            csr[p] = sv;
        }
    }
}

// ===========================================================================
// Slice-local degree-class ordering: bins = [g][dst-slice][class] (g-major,
// 1024 bins). Position space stays g-major; every (dst-slice,g) group is a
// contiguous position range (XCD-local csr writes) and positions within it
// are class-sorted (equal chains per gather wave).
// ===========================================================================
__global__ void __launch_bounds__(256)
deg_class_kernel(const int* __restrict__ cnt2, int* __restrict__ dh,
                 int* __restrict__ degT) {
    __shared__ int lh[NBINS];
    const int tid = threadIdx.x;
    for (int i = tid; i < NBINS; i += 256) lh[i] = 0;
    __syncthreads();
    const int n = blockIdx.x * 256 + tid;
    if (n < N_NODES) {
        int4 c4 = *(const int4*)(cnt2 + 4 * n);
        degT[n] = c4.x + c4.y + c4.z + c4.w;
        const int sb = (n / SLICE_N) * 32;
        atomicAdd(&lh[0 * 256 + sb + min(c4.x, 31)], 1);
        atomicAdd(&lh[1 * 256 + sb + min(c4.y, 31)], 1);
        atomicAdd(&lh[2 * 256 + sb + min(c4.z, 31)], 1);
        atomicAdd(&lh[3 * 256 + sb + min(c4.w, 31)], 1);
    }
    __syncthreads();
    for (int i = tid; i < NBINS; i += 256)
        if (lh[i]) atomicAdd(&dh[i], lh[i]);
}

__global__ void __launch_bounds__(NBINS)
scan_deg_kernel(int* __restrict__ dh, int* __restrict__ dcur) {
    __shared__ int tmp[NBINS];
    const int tid = threadIdx.x;
    int v = dh[tid];
    tmp[tid] = v;
    __syncthreads();
    for (int d = 1; d < NBINS; d <<= 1) {
        int t = (tid >= d) ? tmp[tid - d] : 0;
        __syncthreads();
        tmp[tid] += t;
        __syncthreads();
    }
    int excl = tmp[tid] - v;
    dh[tid] = excl;
    dcur[tid] = excl;
}

// ord[p] = node at global position p; posOf[4n+g] = p (inverse permutation)
__global__ void __launch_bounds__(256)
deg_scatter_kernel(const int* __restrict__ cnt2, int* __restrict__ dcur,
                   int* __restrict__ ord, int* __restrict__ posOf) {
    __shared__ int lcnt[NBINS];
    __shared__ int lbase[NBINS];
    __shared__ u16 lrank[1024];
    __shared__ u16 lcls[1024];
    const int tid = threadIdx.x;
    for (int i = tid; i < NBINS; i += 256) lcnt[i] = 0;
    __syncthreads();
    const int n = blockIdx.x * 256 + tid;
    if (n < N_NODES) {
        int4 c4 = *(const int4*)(cnt2 + 4 * n);
        const int sb = (n / SLICE_N) * 32;
        int dg[4] = { c4.x, c4.y, c4.z, c4.w };
#pragma unroll
        for (int g = 0; g < 4; ++g) {
            int c = g * 256 + sb + min(dg[g], 31);
            lcls[tid * 4 + g]  = (u16)c;
            lrank[tid * 4 + g] = (u16)atomicAdd(&lcnt[c], 1);
        }
    }
    __syncthreads();
    for (int i = tid; i < NBINS; i += 256)
        lbase[i] = lcnt[i] ? atomicAdd(&dcur[i], lcnt[i]) : 0;
    __syncthreads();
    if (n < N_NODES) {
#pragma unroll
        for (int g = 0; g < 4; ++g) {
            int c = lcls[tid * 4 + g];
            int p = lbase[c] + lrank[tid * 4 + g];
            ord[p] = n;
            posOf[4 * n + g] = p;
        }
    }
}

// cursor2[key] = offp[posOf[key]]  (CSR is built directly in permuted layout)
__global__ void __launch_bounds__(256)
cursor_init_kernel(const int* __restrict__ offp, const int* __restrict__ posOf,
                   int* __restrict__ cursor2) {
    int k = blockIdx.x * 256 + threadIdx.x;
    if (k < KEYS) cursor2[k] = offp[posOf[k]];
}

// ===========================================================================
// K4: XCD-sliced gather, strided same-class groups of 8, UNIFORM-TRIP inner
// loop: classes are equal within a group, so the common lenmin trips run with
// NO predication (csr load -> x load -> add); a short predicated tail covers
// odd lengths / bin-boundary groups / class-31 overflow.
// ===========================================================================
__global__ void __launch_bounds__(256)
gatherP_kernel(const float* __restrict__ x, const int* __restrict__ offp,
               const int* __restrict__ csr, const int* __restrict__ ord,
               float* __restrict__ P0, float* __restrict__ P1,
               float* __restrict__ P2, float* __restrict__ P3) {
    const int sid = blockIdx.x & (NXCD - 1);
    const int g = sid >> 1;
    const int h = sid & 1;
    float* __restrict__ P = (g == 0) ? P0 : (g == 1) ? P1 : (g == 2) ? P2 : P3;
    const int chunk = blockIdx.x >> 3;          // < GCH
    const int wid  = threadIdx.x >> 6;
    const int lane = threadIdx.x & 63;
    const int r  = lane >> 5;                   // edge parity
    const int cc = lane & 31;                   // channel within half
    const float* __restrict__ xs = x + h * 32 + cc;
    const int* __restrict__ ordg = ord + g * N_NODES;
    const int* __restrict__ offg = offp + g * N_NODES;

    for (int gi = wid; gi < GPB; gi += 4) {
        const int p0 = (chunk + gi * GCH) * 8;
        int o9[9];
#pragma unroll
        for (int i = 0; i < 9; ++i) o9[i] = offg[p0 + i];
        int ni[8], j[8], e[8];
        float s[8];
        int lenmin = 0x7FFFFFFF;
#pragma unroll
        for (int i = 0; i < 8; ++i) {
            ni[i] = ordg[p0 + i];
            j[i] = o9[i] + r;
            e[i] = o9[i + 1];
            lenmin = min(lenmin, e[i] - o9[i]);
            s[i] = 0.0f;
        }

        // common part: all 8 chains valid -> no predication
        int T = (lenmin - r + 1) >> 1;          // trips at stride 2 from r
        for (int t = 0; t < T; ++t) {
#pragma unroll
            for (int i = 0; i < 8; ++i) {
                int q = csr[j[i]];
                s[i] += xs[(size_t)q * C];
                j[i] += 2;
            }
        }

        // tail: odd remainders, boundary groups, class-31 overflow
        while (true) {
            bool p[8];
            bool any = false;
#pragma unroll
            for (int i = 0; i < 8; ++i) { p[i] = j[i] < e[i]; any = any || p[i]; }
            if (!any) break;

            float t[8];
#pragma unroll
            for (int i = 0; i < 8; ++i) {
                int q = csr[p[i] ? j[i] : 0];
                t[i] = xs[(size_t)q * C];
            }
#pragma unroll
            for (int i = 0; i < 8; ++i) {
                s[i] += p[i] ? t[i] : 0.0f;
                j[i] += 2;
            }
        }

#pragma unroll
        for (int i = 0; i < 8; ++i)
            s[i] += __shfl_xor(s[i], 32);
        if (r == 0) {
#pragma unroll
            for (int i = 0; i < 8; ++i)
                __builtin_nontemporal_store(s[i], &P[(size_t)ni[i] * C + h * 32 + cc]);
        }
    }
}

// ===========================================================================
// K5: GEMM [mean|x](100K x 128) @ [Wl;Wr]^T via mfma_f32_16x16x32_bf16.
// Fused bias+relu+L2norm epilogue. P3 = d_out read-before-write (tile-local).
// ===========================================================================
__global__ void __launch_bounds__(256)
transform_mfma_kernel(const float* __restrict__ x, const int* __restrict__ degT,
                      const float* __restrict__ P0, const float* __restrict__ P1,
                      const float* __restrict__ P2, const float* __restrict__ P3,
                      const float* __restrict__ Wl, const float* __restrict__ bl,
                      const float* __restrict__ Wr, float* __restrict__ out) {
    const int lane = threadIdx.x & 63;
    const int wid  = threadIdx.x >> 6;
    const int col  = lane & 15;
    const int lg   = lane >> 4;

    bf16x8 Bf[4][4];
    float bias[4];
#pragma unroll
    for (int cb = 0; cb < 4; ++cb) {
        const int cc = cb * 16 + col;
        bias[cb] = bl[cc];
#pragma unroll
        for (int ks = 0; ks < 4; ++ks) {
            const int kk0 = ks * 32 + lg * 8;
            const float* W = (kk0 < 64) ? (Wl + (size_t)cc * 64 + kk0)
                                        : (Wr + (size_t)cc * 64 + (kk0 - 64));
            float4 w0 = *(const float4*)W;
            float4 w1 = *(const float4*)(W + 4);
            bf16x8 b;
            b[0]=(short)f2bf(w0.x); b[1]=(short)f2bf(w0.y);
            b[2]=(short)f2bf(w0.z); b[3]=(short)f2bf(w0.w);
            b[4]=(short)f2bf(w1.x); b[5]=(short)f2bf(w1.y);
            b[6]=(short)f2bf(w1.z); b[7]=(short)f2bf(w1.w);
            Bf[cb][ks] = b;
        }
    }

    const int ntiles = N_NODES / 16;
    for (int t = blockIdx.x * 4 + wid; t < ntiles; t += gridDim.x * 4) {
        const int n0 = t * 16;
        const int arow = n0 + col;
        const int deg = degT[arow];
        const float inv = 1.0f / (float)(deg > 1 ? deg : 1);

        f32x4 acc[4];
#pragma unroll
        for (int cb = 0; cb < 4; ++cb) acc[cb] = f32x4{0.f, 0.f, 0.f, 0.f};

#pragma unroll
        for (int ks = 0; ks < 4; ++ks) {
            const int kk0 = ks * 32 + lg * 8;
            bf16x8 a;
            if (kk0 < 64) {
                const float4* p0 = (const float4*)(P0 + (size_t)arow * C + kk0);
                const float4* p1 = (const float4*)(P1 + (size_t)arow * C + kk0);
                const float4* p2 = (const float4*)(P2 + (size_t)arow * C + kk0);
                const float4* p3 = (const float4*)(P3 + (size_t)arow * C + kk0);
                float4 a0 = p0[0], b0 = p1[0], c0 = p2[0], e0 = p3[0];
                float4 a1 = p0[1], b1 = p1[1], c1 = p2[1], e1 = p3[1];
                float s0x = ((a0.x + b0.x) + (c0.x + e0.x)) * inv;
                float s0y = ((a0.y + b0.y) + (c0.y + e0.y)) * inv;
                float s0z = ((a0.z + b0.z) + (c0.z + e0.z)) * inv;
                float s0w = ((a0.w + b0.w) + (c0.w + e0.w)) * inv;
                float s1x = ((a1.x + b1.x) + (c1.x + e1.x)) * inv;
                float s1y = ((a1.y + b1.y) + (c1.y + e1.y)) * inv;
                float s1z = ((a1.z + b1.z) + (c1.z + e1.z)) * inv;
                float s1w = ((a1.w + b1.w) + (c1.w + e1.w)) * inv;
                a[0]=(short)f2bf(s0x); a[1]=(short)f2bf(s0y);
                a[2]=(short)f2bf(s0z); a[3]=(short)f2bf(s0w);
                a[4]=(short)f2bf(s1x); a[5]=(short)f2bf(s1y);
                a[6]=(short)f2bf(s1z); a[7]=(short)f2bf(s1w);
            } else {
                const float4* xp = (const float4*)(x + (size_t)arow * C + (kk0 - 64));
                float4 v0 = xp[0], v1 = xp[1];
                a[0]=(short)f2bf(v0.x); a[1]=(short)f2bf(v0.y);
                a[2]=(short)f2bf(v0.z); a[3]=(short)f2bf(v0.w);
                a[4]=(short)f2bf(v1.x); a[5]=(short)f2bf(v1.y);
                a[6]=(short)f2bf(v1.z); a[7]=(short)f2bf(v1.w);
            }
#pragma unroll
            for (int cb = 0; cb < 4; ++cb)
                acc[cb] = __builtin_amdgcn_mfma_f32_16x16x32_bf16(a, Bf[cb][ks], acc[cb], 0, 0, 0);
        }

#pragma unroll
        for (int jj = 0; jj < 4; ++jj) {
            float v0 = fmaxf(acc[0][jj] + bias[0], 0.0f);
            float v1 = fmaxf(acc[1][jj] + bias[1], 0.0f);
            float v2 = fmaxf(acc[2][jj] + bias[2], 0.0f);
            float v3 = fmaxf(acc[3][jj] + bias[3], 0.0f);
            float sS = (v0 * v0 + v1 * v1) + (v2 * v2 + v3 * v3);
            sS += __shfl_xor(sS, 1);
            sS += __shfl_xor(sS, 2);
            sS += __shfl_xor(sS, 4);
            sS += __shfl_xor(sS, 8);
            float rr = 1.0f / (sqrtf(sS) + EPS);
            const int n = n0 + lg * 4 + jj;
            float* o = out + (size_t)n * C + col;
            o[0]  = v0 * rr;
            o[16] = v1 * rr;
            o[32] = v2 * rr;
            o[48] = v3 * rr;
        }
    }
}

// ===========================================================================
extern "C" void kernel_launch(void* const* d_in, const int* in_sizes, int n_in,
                              void* d_out, int out_size, void* d_ws, size_t ws_size,
                              hipStream_t stream) {
    const float* x    = (const float*)d_in[0];
    const int*   edge = (const int*)d_in[1];
    const float* Wl   = (const float*)d_in[2];
    const float* bl   = (const float*)d_in[3];
    const float* Wr   = (const float*)d_in[4];

    const int E = in_sizes[1] / 2;
    const int* src = edge;
    const int* dst = edge + E;
    const int Epad = (E + 3) & ~3;
    const int bcap = E / NXCD + 32768;

    const size_t nc = (size_t)N_NODES * C;

    // layout: P0 P1 P2 | cnt2 bcur dh dcur degT posOf cursor2 offp bsum
    //         csr ord | bsrc bkey16
    float* P0    = (float*)d_ws;
    float* P1    = P0 + nc;
    float* P2    = P1 + nc;
    int* cnt2    = (int*)(P2 + nc);        // KEYS
    int* bcur    = cnt2 + KEYS;            // 8
    int* dh      = bcur + 8;               // NBINS
    int* dcur    = dh + NBINS;             // NBINS
    int* degT    = dcur + NBINS;           // N
    int* posOf   = degT + N_NODES;         // KEYS
    int* cursor2 = posOf + KEYS;           // KEYS
    int* offp    = cursor2 + KEYS;         // KEYS+4 reserved
    int* bsum    = offp + KEYS + 4;        // 512
    int* csr     = bsum + 512;             // Epad
    int* ord     = csr + Epad;             // KEYS
    int* bsrc    = ord + KEYS;             // 8*bcap
    u16* bkey16  = (u16*)(bsrc + (size_t)8 * bcap);
    float* P3    = (float*)d_out;

    const size_t baseInts = (size_t)KEYS * 5 + 8 + 2 * NBINS + N_NODES + 4 + 512 + Epad;
    const size_t needB = 3ull * nc * 4 + baseInts * 4;
    const size_t needA = needB + (size_t)8 * bcap * 6;

    // zero cnt2 + bcur + dh (adjacent); dcur seeded by scan_deg
    hipMemsetAsync(cnt2, 0, (size_t)(KEYS + 8 + NBINS) * sizeof(int), stream);

    bool tierA = (ws_size >= needA);
    if (tierA) {
        partition_kernel<<<1024, 256, 0, stream>>>(src, dst, bcur, bkey16, bsrc, E, bcap);
        hist2p_kernel<<<NXCD * 256, 256, 0, stream>>>(bcur, bkey16, cnt2, bcap);
    } else {
        hist2_kernel<<<NXCD * 256, 256, 0, stream>>>(src, dst, cnt2, E);
    }

    // slice-local degree-class ordering + permuted scan
    deg_class_kernel<<<NDH, 256, 0, stream>>>(cnt2, dh, degT);
    scan_deg_kernel<<<1, NBINS, 0, stream>>>(dh, dcur);
    deg_scatter_kernel<<<NDH, 256, 0, stream>>>(cnt2, dcur, ord, posOf);
    scan_block_perm_kernel<<<NBLKK, SCAN_BLK, 0, stream>>>(ord, cnt2, offp, bsum, KEYS);
    scan_bsum_kernel<<<1, 512, 0, stream>>>(bsum, NBLKK);
    scan_add_kernel<<<NBLKK, SCAN_BLK, 0, stream>>>(offp, bsum, KEYS, E);
    cursor_init_kernel<<<(KEYS + 255) / 256, 256, 0, stream>>>(offp, posOf, cursor2);

    if (tierA) {
        // time-blocked build: 4 class-range passes (device-ordered via stream)
        build_pass_kernel<<<NXCD * 256, 256, 0, stream>>>(bcur, bkey16, bsrc, cnt2,
                                                          cursor2, csr, bcap, 0, 4);
        build_pass_kernel<<<NXCD * 256, 256, 0, stream>>>(bcur, bkey16, bsrc, cnt2,
                                                          cursor2, csr, bcap, 4, 5);
        build_pass_kernel<<<NXCD * 256, 256, 0, stream>>>(bcur, bkey16, bsrc, cnt2,
                                                          cursor2, csr, bcap, 5, 7);
        build_pass_kernel<<<NXCD * 256, 256, 0, stream>>>(bcur, bkey16, bsrc, cnt2,
                                                          cursor2, csr, bcap, 7, 32);
    } else {
        build2_kernel<<<NXCD * 256, 256, 0, stream>>>(src, dst, cursor2, csr, E);
    }

    gatherP_kernel<<<NXCD * GCH, 256, 0, stream>>>(x, offp, csr, ord, P0, P1, P2, P3);
    transform_mfma_kernel<<<1024, 256, 0, stream>>>(x, degT, P0, P1, P2, P3,
                                                    Wl, bl, Wr, (float*)d_out);
}